// Round 1
// 180.076 us; speedup vs baseline: 1.0473x; 1.0473x over previous
//
#include <hip/hip_runtime.h>
#include <hip/hip_bf16.h>
#include <math.h>

namespace {
constexpr int M  = 48;    // fields
constexpr int D  = 128;   // embedding dim
constexpr int H1 = 68;
constexpr int H2 = 32;
constexpr int H3 = 24;
constexpr int PO = H1 + H2 + H3;  // 124
constexpr int K1 = M  * M;   // 2304
constexpr int K2 = H1 * M;   // 3264
constexpr int HOP1 = 96;     // H1 padded to 3 N-tiles of 32
constexpr int HOP2 = 32;
constexpr int HOP3 = 32;
// ws layout (ushort elements)
constexpr int E1 = (K1 / 8) * HOP1 * 8;   // 221184
constexpr int E2 = (K2 / 8) * HOP2 * 8;   // 104448
constexpr int E3 = ((H2 * M) / 8) * HOP3 * 8; // 49152 (n8-major w3, kept for Gram-free paths)
constexpr int EF = (M * D) * 64;          // 393216  fc1_w bf16
constexpr int EW = E1 + E2 + E3 + EF;     // 768000
constexpr int ET = 24 * 1536;             // 36864  wt3v[o][n] f16 (GEMV layout)
constexpr int X0S = 56;  // x0h f16 stride (112 B rows -> 16B-aligned half8 loads)
constexpr int BAS = 69;  // bufA f16 stride
constexpr int BBS = 33;  // bufB f16 stride
constexpr float BN_SCALE = 0.9995003746877732f;  // 1/sqrt(1+1e-3)
// prep thread-space
constexpr int P1 = (K1 / 8) * HOP1;       // 27648
constexpr int P2 = ((H1 * M) / 8) * HOP2; // 13056
constexpr int P3 = ((H2 * M) / 8) * HOP3; //  6144
constexpr int P4 = EF / 8;                // 49152
constexpr int P5 = ET / 8;                //  4608
}

typedef __attribute__((ext_vector_type(8)))  _Float16 half8;
typedef __attribute__((ext_vector_type(2)))  __fp16   fp16x2;
typedef __attribute__((ext_vector_type(16))) float f32x16;
typedef __attribute__((ext_vector_type(8)))  unsigned short us8;

static __device__ __forceinline__ unsigned short f2bs(float f) {  // bf16 RNE (fc1 path)
    __hip_bfloat16 h = __float2bfloat16(f);
    return __builtin_bit_cast(unsigned short, h);
}
static __device__ __forceinline__ unsigned short f2hs(float f) {  // f16 RNE
    _Float16 h = (_Float16)f;
    return __builtin_bit_cast(unsigned short, h);
}
static __device__ __forceinline__ float hs2f(unsigned short u) {  // f16 -> f32
    return (float)__builtin_bit_cast(_Float16, u);
}
static __device__ __forceinline__ unsigned int cvt2(float a, float b) {
    fp16x2 h = __builtin_amdgcn_cvt_pkrtz(a, b);
    return __builtin_bit_cast(unsigned int, h);
}

// ---------------- prep: transpose+convert weights into d_ws ------------------
// n8-major MFMA layouts for w1/w2/w3, bf16 copy of fc1_w, plus wt3v[o][n] f16
// (o-major, n-contiguous) for the pool3 GEMV.
__global__ __launch_bounds__(256)
void prep_kernel(const float* __restrict__ w1, const float* __restrict__ w2,
                 const float* __restrict__ w3, const float* __restrict__ fc1w,
                 unsigned short* __restrict__ ws)
{
    const int tid = blockIdx.x * 256 + threadIdx.x;
    us8 v;
    if (tid < P1) {
        const int k8 = tid / HOP1, o = tid - k8 * HOP1;
        #pragma unroll
        for (int i = 0; i < 8; ++i)
            v[i] = (o < H1) ? f2hs(w1[(k8 * 8 + i) * H1 + o]) : (unsigned short)0;
        *(uint4*)(ws + (size_t)k8 * (HOP1 * 8) + o * 8) = __builtin_bit_cast(uint4, v);
    } else if (tid < P1 + P2) {
        const int x = tid - P1;
        const int k8 = x >> 5, o = x & 31;
        #pragma unroll
        for (int i = 0; i < 8; ++i)
            v[i] = f2hs(w2[(k8 * 8 + i) * H2 + o]);
        *(uint4*)(ws + E1 + (size_t)k8 * (HOP2 * 8) + o * 8) = __builtin_bit_cast(uint4, v);
    } else if (tid < P1 + P2 + P3) {
        const int x = tid - (P1 + P2);
        const int k8 = x >> 5, o = x & 31;
        #pragma unroll
        for (int i = 0; i < 8; ++i)
            v[i] = (o < H3) ? f2hs(w3[(k8 * 8 + i) * H3 + o]) : (unsigned short)0;
        *(uint4*)(ws + E1 + E2 + (size_t)k8 * (HOP3 * 8) + o * 8) = __builtin_bit_cast(uint4, v);
    } else if (tid < P1 + P2 + P3 + P4) {
        const int x = tid - (P1 + P2 + P3);
        const float4 a = ((const float4*)fc1w)[x * 2];
        const float4 b = ((const float4*)fc1w)[x * 2 + 1];
        v[0] = f2bs(a.x); v[1] = f2bs(a.y); v[2] = f2bs(a.z); v[3] = f2bs(a.w);
        v[4] = f2bs(b.x); v[5] = f2bs(b.y); v[6] = f2bs(b.z); v[7] = f2bs(b.w);
        *(uint4*)(ws + E1 + E2 + E3 + (size_t)x * 8) = __builtin_bit_cast(uint4, v);
    } else if (tid < P1 + P2 + P3 + P4 + P5) {
        const int x = tid - (P1 + P2 + P3 + P4);
        const int o = x / 192, n0 = (x - o * 192) * 8;
        #pragma unroll
        for (int i = 0; i < 8; ++i)
            v[i] = f2hs(w3[(n0 + i) * H3 + o]);
        *(uint4*)(ws + EW + (size_t)o * 1536 + n0) = __builtin_bit_cast(uint4, v);
    }
}

// ---------------- CIN layer via 32x32x16 f16 MFMA; block = batch row ----------
// 8 waves = (tile: 4 x 32 rows over 128 d) x (khalf: 2). A-build: 4 v_pk_mul_f16.
// NS-slot B rotation (NS=12 for layer 2: ~240cy prefetch cover vs ~200cy+ L2
// latency; layer 1 stays NS=3 — deeper rotation there busts the 128-VGPR/wave
// budget at 2 blocks/CU). DUALOUT: khalf waves store DISJOINT buffers (ob0/ob1)
// -> single barrier, no RMW; consumer sums on read. XKDUAL: xk = f16(a0)+f16(a1).
// NO device-scope fences (R10 regression).
template<int KTOT, int HO, int NT, int HOP, int NS, bool DUALOUT, bool XKDUAL>
__device__ __forceinline__ void cin_mfma(
    const unsigned short* __restrict__ x0h,
    const unsigned short* __restrict__ xk0, const unsigned short* __restrict__ xk1,
    int xkstride,
    const unsigned short* __restrict__ wt,
    unsigned short* __restrict__ ob0, unsigned short* __restrict__ ob1,
    int outstride,
    float* __restrict__ pool, int poff, int t)
{
    const int lane  = t & 63;
    const int w     = t >> 6;
    const int tile  = w & 3;
    const int khalf = w >> 2;
    const int o0 = lane & 31, h2 = lane >> 5;
    const int dl = tile * 32 + o0;          // this lane's A-row (local d, 0..127)
    constexpr int KS = KTOT / 16;
    constexpr int KH = KS / 2;
    static_assert(KH % 6 == 0, "K-half must be a multiple of 6 ksteps");
    static_assert(NS == 3 || NS == 6 || NS == 12, "unsupported NS");
    const int ks0 = khalf * KH;
    const int kb0 = ks0 / 3;

    half8 q8[3];
    #pragma unroll
    for (int p = 0; p < 3; ++p)
        q8[p] = *(const half8*)(x0h + dl * X0S + (2 * p + h2) * 8);

    f32x16 acc[NT];
    #pragma unroll
    for (int nt = 0; nt < NT; ++nt)
        #pragma unroll
        for (int r = 0; r < 16; ++r) acc[nt][r] = 0.f;

    const unsigned short* xr0 = xk0 + dl * xkstride;
    const unsigned short* xr1 = XKDUAL ? (xk1 + dl * xkstride) : nullptr;
    const unsigned short* wb = wt + (size_t)(h2 * HOP + o0) * 8;

    auto xsplat = [&](int k) -> half8 {
        unsigned int xp;
        if (XKDUAL) {
            const float xv = hs2f(xr0[k]) + hs2f(xr1[k]);
            xp = cvt2(xv, xv);
        } else {
            xp = (unsigned int)xr0[k] * 0x10001u;
        }
        uint4 s; s.x = xp; s.y = xp; s.z = xp; s.w = xp;
        return __builtin_bit_cast(half8, s);
    };

    uint4 br[NS][NT];
    auto loadB = [&](int ks, uint4* b) {
        const unsigned short* p = wb + (size_t)ks * (2 * HOP * 8);
        #pragma unroll
        for (int nt = 0; nt < NT; ++nt)
            b[nt] = *(const uint4*)(p + nt * 256);
    };
    auto phase = [&](int p, half8 xs, const uint4* b) {
        const half8 av = xs * q8[p];
        #pragma unroll
        for (int nt = 0; nt < NT; ++nt)
            acc[nt] = __builtin_amdgcn_mfma_f32_32x32x16_f16(
                av, __builtin_bit_cast(half8, b[nt]), acc[nt], 0, 0, 0);
    };

    #pragma unroll
    for (int s = 0; s < NS; ++s) loadB(ks0 + s, br[s]);
    half8 xs0 = xsplat(kb0);

    if constexpr (NS == 12) {
        // 12-slot rotation: slot(phase p) = p % 12; 12-phase double-groups.
        // Trailing reloads past KH read harmlessly into the next ws region
        // (allocated, never consumed).
        constexpr int NIT = KH / 12;
        static_assert(KH % 12 == 0 || KH % 12 == 6, "NS=12 tail must be 0 or 6 phases");
        #pragma unroll 1
        for (int it = 0; it < NIT; ++it) {
            const int g  = ks0 + it * 12;
            const int kb = kb0 + it * 4;
            const half8 xs1 = xsplat(kb + 1);
            phase(0, xs0, br[0]);   loadB(g + 12 + 0,  br[0]);
            phase(1, xs0, br[1]);   loadB(g + 12 + 1,  br[1]);
            phase(2, xs0, br[2]);   loadB(g + 12 + 2,  br[2]);
            const half8 xs2 = xsplat(kb + 2);
            phase(0, xs1, br[3]);   loadB(g + 12 + 3,  br[3]);
            phase(1, xs1, br[4]);   loadB(g + 12 + 4,  br[4]);
            phase(2, xs1, br[5]);   loadB(g + 12 + 5,  br[5]);
            const half8 xs3 = xsplat(kb + 3);
            phase(0, xs2, br[6]);   loadB(g + 12 + 6,  br[6]);
            phase(1, xs2, br[7]);   loadB(g + 12 + 7,  br[7]);
            phase(2, xs2, br[8]);   loadB(g + 12 + 8,  br[8]);
            const half8 xsn = xsplat(kb + 4);   // last iter: feeds the 6-phase tail
            phase(0, xs3, br[9]);   loadB(g + 12 + 9,  br[9]);
            phase(1, xs3, br[10]);  loadB(g + 12 + 10, br[10]);
            phase(2, xs3, br[11]);  loadB(g + 12 + 11, br[11]);
            xs0 = xsn;
        }
        if constexpr (KH % 12 == 6) {
            // slots 0..5 were reloaded in the last iteration with exactly
            // phases ks0+KH-6 .. ks0+KH-1.
            const int kb = kb0 + NIT * 4;
            const half8 xs1 = xsplat(kb + 1);
            phase(0, xs0, br[0]);
            phase(1, xs0, br[1]);
            phase(2, xs0, br[2]);
            phase(0, xs1, br[3]);
            phase(1, xs1, br[4]);
            phase(2, xs1, br[5]);
        }
    } else {
        #pragma unroll 1
        for (int it = 0; it < KH / 6; ++it) {
            const int g  = ks0 + it * 6;
            const int kb = kb0 + it * 2;
            const half8 xs1 = xsplat(kb + 1);
            phase(0, xs0, br[0 % NS]);  loadB(g + NS + 0, br[0 % NS]);
            phase(1, xs0, br[1 % NS]);  loadB(g + NS + 1, br[1 % NS]);
            phase(2, xs0, br[2 % NS]);  loadB(g + NS + 2, br[2 % NS]);
            const half8 xsn = xsplat(kb + 2);   // in-row-pad at last iter (dead value)
            phase(0, xs1, br[3 % NS]);  loadB(g + NS + 3, br[3 % NS]);
            phase(1, xs1, br[4 % NS]);  loadB(g + NS + 4, br[4 % NS]);
            phase(2, xs1, br[5 % NS]);  loadB(g + NS + 5, br[5 % NS]);
            xs0 = xsn;
        }
    }

    // epilogue
    const int dbase = tile * 32 + 4 * h2;
    if (DUALOUT) {
        unsigned short* ob = khalf ? ob1 : ob0;
        #pragma unroll
        for (int nt = 0; nt < NT; ++nt) {
            const int o = nt * 32 + o0;
            if (o < HO) {
                float s = 0.f;
                #pragma unroll
                for (int r = 0; r < 16; ++r) s += acc[nt][r];
                #pragma unroll
                for (int r = 0; r < 16; ++r)
                    ob[(dbase + (r & 3) + 8 * (r >> 2)) * outstride + o] = f2hs(acc[nt][r]);
                s += __shfl_xor(s, 32, 64);
                if (lane < 32) atomicAdd(&pool[poff + o], s);
            }
        }
        __syncthreads();              // both partial buffers visible
    } else {
        #pragma unroll
        for (int nt = 0; nt < NT; ++nt) {
            const int o = nt * 32 + o0;
            if (o < HO) {
                float s = 0.f;
                #pragma unroll
                for (int r = 0; r < 16; ++r) s += acc[nt][r];
                if (khalf == 0) {
                    #pragma unroll
                    for (int r = 0; r < 16; ++r)
                        ob0[(dbase + (r & 3) + 8 * (r >> 2)) * outstride + o] = f2hs(acc[nt][r]);
                }
                s += __shfl_xor(s, 32, 64);
                if (lane < 32) atomicAdd(&pool[poff + o], s);
            }
        }
        __syncthreads();
        if (khalf == 1) {
            #pragma unroll
            for (int nt = 0; nt < NT; ++nt) {
                const int o = nt * 32 + o0;
                if (o < HO) {
                    #pragma unroll
                    for (int r = 0; r < 16; ++r) {
                        const int idx = (dbase + (r & 3) + 8 * (r >> 2)) * outstride + o;
                        ob0[idx] = f2hs(hs2f(ob0[idx]) + acc[nt][r]);
                    }
                }
            }
        }
        __syncthreads();
    }
}

__global__ __launch_bounds__(512, 4)
void dcin_kernel(const int*   __restrict__ x,
                 const float* __restrict__ emb,
                 const unsigned short* __restrict__ ws,
                 const float* __restrict__ lin_w, const float* __restrict__ lin_b,
                 const float* __restrict__ fc1_b,
                 const float* __restrict__ bn1_g, const float* __restrict__ bn1_b,
                 const float* __restrict__ fc2_w, const float* __restrict__ fc2_b,
                 const float* __restrict__ bn2_g, const float* __restrict__ bn2_b,
                 const float* __restrict__ fc3_w, const float* __restrict__ fc3_b,
                 const float* __restrict__ bn3_g, const float* __restrict__ bn3_b,
                 const float* __restrict__ out_w, const float* __restrict__ out_b,
                 float* __restrict__ out)
{
    __shared__ __align__(16) unsigned short x0h  [D * X0S + 16]; // 14368 B
    __shared__ __align__(16) unsigned short bufA0[D * BAS];      // 17664 B (khalf0 partial)
    __shared__ __align__(16) unsigned short bufA1[D * BAS];      // 17664 B (khalf1 partial)
    __shared__ __align__(16) unsigned short bufB [D * BBS];      //  8448 B (L2 khalf0 partial)
    __shared__ __align__(16) unsigned short bufB1[D * BBS];      //  8448 B (L2 khalf1 partial)
    __shared__ float pool_s[PO];
    __shared__ int   sx[M];
    __shared__ float h1s[64], h2s[48], h3s[24];
    float* const red2 = (float*)bufA0;                // 768 floats (bytes 0..3072)
    float* const Gs   = (float*)(bufA0 + 2048);       // 1536 floats (bytes 4096..10240)

    const unsigned short* wt1   = ws;
    const unsigned short* wt2   = ws + E1;
    const unsigned short* fc1b  = ws + E1 + E2 + E3;
    const unsigned short* wt3v  = ws + EW;            // [24][1536] f16

    const int b = blockIdx.x;
    const int t = threadIdx.x;

    if (t < M) sx[t] = x[b * M + t];
    if (t < PO) pool_s[t] = 0.f;
    __syncthreads();

    // gather x0h[dl][j] = f16(emb[sx[j]][dl]), all 128 d; j-fast writes
    for (int i = t; i < M * (D / 4); i += 512) {
        const int c = i / 48;              // float4 index 0..31
        const int j = i - c * 48;
        const float4 v = ((const float4*)(emb + (size_t)sx[j] * D))[c];
        x0h[(4 * c + 0) * X0S + j] = f2hs(v.x);
        x0h[(4 * c + 1) * X0S + j] = f2hs(v.y);
        x0h[(4 * c + 2) * X0S + j] = f2hs(v.z);
        x0h[(4 * c + 3) * X0S + j] = f2hs(v.w);
    }
    __syncthreads();

    // ---- CIN layer 1: dual-output (one barrier, no RMW) ----
    cin_mfma<K1, H1, 3, HOP1, 3, true, false>(
        x0h, x0h, nullptr, X0S, wt1, bufA0, bufA1, BAS, pool_s, 0, t);
    // ---- CIN layer 2: xk = bufA0+bufA1 on read; dual output bufB/bufB1
    //      (one barrier, no RMW); NS=12 deep B prefetch ----
    cin_mfma<K2, H2, 1, HOP2, 12, true, true>(
        x0h, bufA0, bufA1, BAS, wt2, bufB, bufB1, BBS, pool_s, H1, t);
    // bufB/bufB1 = C2 partials; bufA0/A1 dead (red2/Gs alias live from here).

    // ---- layer 3 via Gram: pool3[o] = sum_n G[n] W3[n][o],
    //      G[k][j] = sum_d C2[d][k] * x0h[d][j]  (exact pooling identity),
    //      C2 = bufB + bufB1 summed on read.
    //      Waves 0,1: Gram j-tiles. Waves 2..7: fc1 partials (concurrent). ----
    const int w = t >> 6;
    if (w < 2) {
        const int lane = t & 63, m = lane & 31, h2g = lane >> 5;
        f32x16 g;
        #pragma unroll
        for (int r = 0; r < 16; ++r) g[r] = 0.f;
        #pragma unroll 1
        for (int s = 0; s < 8; ++s) {      // K = 128 d, 16 per MFMA
            us8 a8, b8;
            #pragma unroll
            for (int i = 0; i < 8; ++i) {
                const int d = s * 16 + h2g * 8 + i;
                a8[i] = f2hs(hs2f(bufB [d * BBS + m]) +
                             hs2f(bufB1[d * BBS + m]));  // A[k=m][d] = C2[d][m]
                b8[i] = x0h[d * X0S + w * 32 + m];       // B[d][j=w*32+m]
            }
            g = __builtin_amdgcn_mfma_f32_32x32x16_f16(
                __builtin_bit_cast(half8, a8), __builtin_bit_cast(half8, b8), g, 0, 0, 0);
        }
        #pragma unroll
        for (int r = 0; r < 16; ++r) {
            const int k = (r & 3) + 8 * (r >> 2) + 4 * h2g;
            const int j = w * 32 + m;
            if (j < 48) Gs[k * 48 + j] = g[r];
        }
    } else {
        // fc1 partial (bf16 weights, f16 x0): waves 2..7, 12 parts x 4 fields
        const int tl = t - 128;
        const int u2 = (tl & 31) * 2;
        const int part = tl >> 5;          // 0..11
        float a0 = 0.f, a1 = 0.f;
        for (int j = part * 4; j < part * 4 + 4; ++j) {
            const unsigned short* xr = x0h + j;
            #pragma unroll 8
            for (int d = 0; d < D; ++d) {
                const float xv = hs2f(xr[d * X0S]);
                const unsigned int wp = *(const unsigned int*)(
                    fc1b + ((size_t)j * D + d) * 64 + u2);
                a0 = fmaf(xv, __builtin_bit_cast(float, wp << 16), a0);
                a1 = fmaf(xv, __builtin_bit_cast(float, wp & 0xffff0000u), a1);
            }
        }
        red2[tl * 2]     = a0;
        red2[tl * 2 + 1] = a1;
    }
    __syncthreads();

    // ---- pool3 GEMV (384 thr, contiguous wt3v half8 reads) + h1 combine ----
    if (t < 384) {
        const int o = t % 24, seg = t / 24;   // 16 segs x 96 n's
        const unsigned short* wrow = wt3v + (size_t)o * 1536 + seg * 96;
        const float* gseg = Gs + seg * 96;
        float a = 0.f;
        #pragma unroll 2
        for (int n8 = 0; n8 < 12; ++n8) {
            const us8 wv = *(const us8*)(wrow + n8 * 8);
            #pragma unroll
            for (int i = 0; i < 8; ++i)
                a = fmaf(gseg[n8 * 8 + i], hs2f(wv[i]), a);
        }
        atomicAdd(&pool_s[H1 + H2 + o], a);
    } else if (t < 448) {
        const int uo = t - 384;
        float v = fc1_b[uo];
        #pragma unroll
        for (int p = 0; p < 12; ++p)
            v += red2[(p * 32 + (uo >> 1)) * 2 + (uo & 1)];
        v = fmaxf(v, 0.f);
        h1s[uo] = bn1_g[uo] * v * BN_SCALE + bn1_b[uo];
    }
    __syncthreads();

    if (t < 48) {
        float a = fc2_b[t];
        #pragma unroll 4
        for (int u = 0; u < 64; ++u) a = fmaf(h1s[u], fc2_w[u * 48 + t], a);
        a = tanhf(a);
        h2s[t] = bn2_g[t] * a * BN_SCALE + bn2_b[t];
    }
    __syncthreads();

    if (t < 24) {
        float a = fc3_b[t];
        #pragma unroll 4
        for (int u = 0; u < 48; ++u) a = fmaf(h2s[u], fc3_w[u * 24 + t], a);
        a = tanhf(a);
        h3s[t] = bn3_g[t] * a * BN_SCALE + bn3_b[t];
    }
    __syncthreads();

    if (t == 0) {
        float s = lin_b[0];
        for (int j = 0; j < M; ++j) s += (float)sx[j] * lin_w[j];
        const float slin = tanhf(s);
        float z = out_b[0];
        #pragma unroll 4
        for (int i = 0; i < H3; ++i) z = fmaf(h3s[i], out_w[i], z);
        z = fmaf(slin, out_w[H3], z);
        #pragma unroll 4
        for (int i = 0; i < PO; ++i)
            z = fmaf(pool_s[i], out_w[H3 + 1 + i], z);
        out[b] = 1.f / (1.f + expf(-z));
    }
}

extern "C" void kernel_launch(void* const* d_in, const int* in_sizes, int n_in,
                              void* d_out, int out_size, void* d_ws, size_t ws_size,
                              hipStream_t stream) {
    (void)in_sizes; (void)n_in; (void)ws_size; (void)out_size;
    const int*   x     = (const int*)  d_in[0];
    const float* emb   = (const float*)d_in[1];
    const float* w1    = (const float*)d_in[2];
    const float* w2    = (const float*)d_in[3];
    const float* w3    = (const float*)d_in[4];
    const float* lin_w = (const float*)d_in[5];
    const float* lin_b = (const float*)d_in[6];
    const float* fc1_w = (const float*)d_in[7];
    const float* fc1_b = (const float*)d_in[8];
    const float* bn1_g = (const float*)d_in[9];
    const float* bn1_b = (const float*)d_in[10];
    const float* fc2_w = (const float*)d_in[11];
    const float* fc2_b = (const float*)d_in[12];
    const float* bn2_g = (const float*)d_in[13];
    const float* bn2_b = (const float*)d_in[14];
    const float* fc3_w = (const float*)d_in[15];
    const float* fc3_b = (const float*)d_in[16];
    const float* bn3_g = (const float*)d_in[17];
    const float* bn3_b = (const float*)d_in[18];
    const float* out_w = (const float*)d_in[19];
    const float* out_b = (const float*)d_in[20];
    unsigned short* ws = (unsigned short*)d_ws;

    const int prep_threads = P1 + P2 + P3 + P4 + P5;
    prep_kernel<<<(prep_threads + 255) / 256, 256, 0, stream>>>(w1, w2, w3, fc1_w, ws);

    dcin_kernel<<<512, 512, 0, stream>>>(
        x, emb, ws,
        lin_w, lin_b, fc1_b, bn1_g, bn1_b,
        fc2_w, fc2_b, bn2_g, bn2_b,
        fc3_w, fc3_b, bn3_g, bn3_b,
        out_w, out_b, (float*)d_out);
}

// Round 2
// 169.322 us; speedup vs baseline: 1.1138x; 1.0635x over previous
//
#include <hip/hip_runtime.h>
#include <hip/hip_bf16.h>
#include <math.h>

namespace {
constexpr int M  = 48;    // fields
constexpr int D  = 128;   // embedding dim
constexpr int H1 = 68;
constexpr int H2 = 32;
constexpr int H3 = 24;
constexpr int PO = H1 + H2 + H3;  // 124
constexpr int K2 = H1 * M;   // 3264
constexpr int HOP1 = 96;     // H1 padded to 3 N-tiles of 32
constexpr int HOP2 = 32;
constexpr int HOP3 = 32;
// Layer-1 symmetric fold: lower triangle j<=k, rows padded to 16.
// rows 0..15: 1 kstep, 16..31: 2, 32..47: 3  => 96 ksteps (vs 144 unfolded).
constexpr int KS1 = 96;
// ws layout (ushort elements)
constexpr int E1 = KS1 * 2 * HOP1 * 8;    // 147456  folded w1, n8-major
constexpr int E2 = (K2 / 8) * HOP2 * 8;   // 104448
constexpr int E3 = ((H2 * M) / 8) * HOP3 * 8; // 49152 (n8-major w3, kept for Gram-free paths)
constexpr int EF = (M * D) * 64;          // 393216  fc1_w bf16
constexpr int EW = E1 + E2 + E3 + EF;     // 694272
constexpr int ET = 24 * 1536;             // 36864  wt3v[o][n] f16 (GEMV layout)
constexpr int X0S = 56;  // x0h f16 stride (112 B rows -> 16B-aligned half8 loads)
constexpr int BAS = 69;  // bufA f16 stride
constexpr int BBS = 33;  // bufB f16 stride
constexpr float BN_SCALE = 0.9995003746877732f;  // 1/sqrt(1+1e-3)
// prep thread-space
constexpr int P1 = KS1 * 2 * HOP1;        // 18432
constexpr int P2 = ((H1 * M) / 8) * HOP2; // 13056
constexpr int P3 = ((H2 * M) / 8) * HOP3; //  6144
constexpr int P4 = EF / 8;                // 49152
constexpr int P5 = ET / 8;                //  4608

// kstep -> (row k, jblock p) for the folded layer-1 ordering (k-major).
// base(k): k<16 -> k ; 16..31 -> 16+2(k-16) ; 32..47 -> 48+3(k-32).
constexpr int c1_k(int ks) {
    return (ks < 16) ? ks : (ks < 48) ? 16 + ((ks - 16) >> 1) : 32 + (ks - 48) / 3;
}
constexpr int c1_p(int ks) {
    return (ks < 16) ? 0 : (ks < 48) ? ((ks - 16) & 1) : (ks - 48) % 3;
}
}

typedef __attribute__((ext_vector_type(8)))  _Float16 half8;
typedef __attribute__((ext_vector_type(2)))  __fp16   fp16x2;
typedef __attribute__((ext_vector_type(16))) float f32x16;
typedef __attribute__((ext_vector_type(8)))  unsigned short us8;

static __device__ __forceinline__ unsigned short f2bs(float f) {  // bf16 RNE (fc1 path)
    __hip_bfloat16 h = __float2bfloat16(f);
    return __builtin_bit_cast(unsigned short, h);
}
static __device__ __forceinline__ unsigned short f2hs(float f) {  // f16 RNE
    _Float16 h = (_Float16)f;
    return __builtin_bit_cast(unsigned short, h);
}
static __device__ __forceinline__ float hs2f(unsigned short u) {  // f16 -> f32
    return (float)__builtin_bit_cast(_Float16, u);
}
static __device__ __forceinline__ unsigned int cvt2(float a, float b) {
    fp16x2 h = __builtin_amdgcn_cvt_pkrtz(a, b);
    return __builtin_bit_cast(unsigned int, h);
}

// ---------------- prep: transpose+convert weights into d_ws ------------------
// Folded n8-major layout for w1 (symmetric pair-sum), n8-major for w2/w3,
// bf16 copy of fc1_w, plus wt3v[o][n] f16 for the pool3 GEMV.
__global__ __launch_bounds__(256)
void prep_kernel(const float* __restrict__ w1, const float* __restrict__ w2,
                 const float* __restrict__ w3, const float* __restrict__ fc1w,
                 unsigned short* __restrict__ ws)
{
    const int tid = blockIdx.x * 256 + threadIdx.x;
    us8 v;
    if (tid < P1) {
        const int k8 = tid / HOP1, o = tid - k8 * HOP1;  // k8 = 0..191
        const int ks = k8 >> 1, hh = k8 & 1;
        const int k = c1_k(ks), p = c1_p(ks);
        #pragma unroll
        for (int i = 0; i < 8; ++i) {
            const int j = p * 16 + hh * 8 + i;
            float wv = 0.f;
            if (o < H1) {
                if (j < k)       wv = w1[(k * M + j) * H1 + o] + w1[(j * M + k) * H1 + o];
                else if (j == k) wv = w1[(k * M + k) * H1 + o];
            }
            v[i] = f2hs(wv);
        }
        *(uint4*)(ws + (size_t)k8 * (HOP1 * 8) + o * 8) = __builtin_bit_cast(uint4, v);
    } else if (tid < P1 + P2) {
        const int x = tid - P1;
        const int k8 = x >> 5, o = x & 31;
        #pragma unroll
        for (int i = 0; i < 8; ++i)
            v[i] = f2hs(w2[(k8 * 8 + i) * H2 + o]);
        *(uint4*)(ws + E1 + (size_t)k8 * (HOP2 * 8) + o * 8) = __builtin_bit_cast(uint4, v);
    } else if (tid < P1 + P2 + P3) {
        const int x = tid - (P1 + P2);
        const int k8 = x >> 5, o = x & 31;
        #pragma unroll
        for (int i = 0; i < 8; ++i)
            v[i] = (o < H3) ? f2hs(w3[(k8 * 8 + i) * H3 + o]) : (unsigned short)0;
        *(uint4*)(ws + E1 + E2 + (size_t)k8 * (HOP3 * 8) + o * 8) = __builtin_bit_cast(uint4, v);
    } else if (tid < P1 + P2 + P3 + P4) {
        const int x = tid - (P1 + P2 + P3);
        const float4 a = ((const float4*)fc1w)[x * 2];
        const float4 b = ((const float4*)fc1w)[x * 2 + 1];
        v[0] = f2bs(a.x); v[1] = f2bs(a.y); v[2] = f2bs(a.z); v[3] = f2bs(a.w);
        v[4] = f2bs(b.x); v[5] = f2bs(b.y); v[6] = f2bs(b.z); v[7] = f2bs(b.w);
        *(uint4*)(ws + E1 + E2 + E3 + (size_t)x * 8) = __builtin_bit_cast(uint4, v);
    } else if (tid < P1 + P2 + P3 + P4 + P5) {
        const int x = tid - (P1 + P2 + P3 + P4);
        const int o = x / 192, n0 = (x - o * 192) * 8;
        #pragma unroll
        for (int i = 0; i < 8; ++i)
            v[i] = f2hs(w3[(n0 + i) * H3 + o]);
        *(uint4*)(ws + EW + (size_t)o * 1536 + n0) = __builtin_bit_cast(uint4, v);
    }
}

// ---------------- layer-1 (symmetric-folded) inner loop ----------------------
// Full 48-phase unroll per khalf; kstep -> (row,jblock) is compile-time, so the
// per-row splat comes from one LDS u16 read and q8[p] indexing stays static.
// NS=3 register rotation, prefetch lead 3.
template<int KHALF>
__device__ __forceinline__ void cin1_loop(
    const half8 (&q8)[3], const unsigned short* __restrict__ xr,
    const unsigned short* __restrict__ wb, f32x16 (&acc)[3])
{
    constexpr int PH0 = KHALF * 48;
    uint4 br[3][3];
    auto loadB = [&](int ks, uint4* b) {
        const unsigned short* p = wb + (size_t)ks * (2 * HOP1 * 8);
        #pragma unroll
        for (int nt = 0; nt < 3; ++nt)
            b[nt] = *(const uint4*)(p + nt * 256);
    };
    auto phase = [&](int p, half8 xs, const uint4* b) {
        const half8 av = xs * q8[p];
        #pragma unroll
        for (int nt = 0; nt < 3; ++nt)
            acc[nt] = __builtin_amdgcn_mfma_f32_32x32x16_f16(
                av, __builtin_bit_cast(half8, b[nt]), acc[nt], 0, 0, 0);
    };
    loadB(PH0 + 0, br[0]);
    loadB(PH0 + 1, br[1]);
    loadB(PH0 + 2, br[2]);
    half8 xs{};
    #pragma unroll
    for (int ph = 0; ph < 48; ++ph) {
        if (c1_p(PH0 + ph) == 0) {   // new row: refresh splat x0[dl][k]
            const unsigned int xp = (unsigned int)xr[c1_k(PH0 + ph)] * 0x10001u;
            uint4 s; s.x = xp; s.y = xp; s.z = xp; s.w = xp;
            xs = __builtin_bit_cast(half8, s);
        }
        phase(c1_p(PH0 + ph), xs, br[ph % 3]);
        if (ph < 45) loadB(PH0 + ph + 3, br[ph % 3]);
    }
}

// Layer-1 shell: 8 waves = (tile: 4 x 32 d-rows) x (khalf: rows 0..31 / 32..47).
// Dual-output epilogue (disjoint partial buffers, one barrier, no RMW).
__device__ __forceinline__ void cin1_sym(
    const unsigned short* __restrict__ x0h,
    const unsigned short* __restrict__ wt,
    unsigned short* __restrict__ ob0, unsigned short* __restrict__ ob1,
    float* __restrict__ pool, int t)
{
    const int lane  = t & 63;
    const int w     = t >> 6;
    const int tile  = w & 3;
    const int khalf = w >> 2;
    const int o0 = lane & 31, h2 = lane >> 5;
    const int dl = tile * 32 + o0;

    half8 q8[3];
    #pragma unroll
    for (int p = 0; p < 3; ++p)
        q8[p] = *(const half8*)(x0h + dl * X0S + (2 * p + h2) * 8);

    f32x16 acc[3];
    #pragma unroll
    for (int nt = 0; nt < 3; ++nt)
        #pragma unroll
        for (int r = 0; r < 16; ++r) acc[nt][r] = 0.f;

    const unsigned short* xr = x0h + dl * X0S;
    const unsigned short* wb = wt + (size_t)(h2 * HOP1 + o0) * 8;

    if (khalf == 0) cin1_loop<0>(q8, xr, wb, acc);
    else            cin1_loop<1>(q8, xr, wb, acc);

    const int dbase = tile * 32 + 4 * h2;
    unsigned short* ob = khalf ? ob1 : ob0;
    #pragma unroll
    for (int nt = 0; nt < 3; ++nt) {
        const int o = nt * 32 + o0;
        if (o < H1) {
            float s = 0.f;
            #pragma unroll
            for (int r = 0; r < 16; ++r) s += acc[nt][r];
            #pragma unroll
            for (int r = 0; r < 16; ++r)
                ob[(dbase + (r & 3) + 8 * (r >> 2)) * BAS + o] = f2hs(acc[nt][r]);
            s += __shfl_xor(s, 32, 64);
            if (lane < 32) atomicAdd(&pool[o], s);
        }
    }
    __syncthreads();
}

// ---------------- generic CIN layer (used for layer 2) -----------------------
// 8 waves = (tile: 4 x 32 rows over 128 d) x (khalf: 2). A-build: 4 v_pk_mul_f16.
// NS-slot B rotation (NS=12: ~240cy prefetch cover vs ~200cy+ L2 latency).
// DUALOUT: khalf waves store DISJOINT buffers -> single barrier, no RMW.
// XKDUAL: xk = f16(a0)+f16(a1). NO device-scope fences (R10 regression).
template<int KTOT, int HO, int NT, int HOP, int NS, bool DUALOUT, bool XKDUAL>
__device__ __forceinline__ void cin_mfma(
    const unsigned short* __restrict__ x0h,
    const unsigned short* __restrict__ xk0, const unsigned short* __restrict__ xk1,
    int xkstride,
    const unsigned short* __restrict__ wt,
    unsigned short* __restrict__ ob0, unsigned short* __restrict__ ob1,
    int outstride,
    float* __restrict__ pool, int poff, int t)
{
    const int lane  = t & 63;
    const int w     = t >> 6;
    const int tile  = w & 3;
    const int khalf = w >> 2;
    const int o0 = lane & 31, h2 = lane >> 5;
    const int dl = tile * 32 + o0;          // this lane's A-row (local d, 0..127)
    constexpr int KS = KTOT / 16;
    constexpr int KH = KS / 2;
    static_assert(KH % 6 == 0, "K-half must be a multiple of 6 ksteps");
    static_assert(NS == 3 || NS == 6 || NS == 12, "unsupported NS");
    const int ks0 = khalf * KH;
    const int kb0 = ks0 / 3;

    half8 q8[3];
    #pragma unroll
    for (int p = 0; p < 3; ++p)
        q8[p] = *(const half8*)(x0h + dl * X0S + (2 * p + h2) * 8);

    f32x16 acc[NT];
    #pragma unroll
    for (int nt = 0; nt < NT; ++nt)
        #pragma unroll
        for (int r = 0; r < 16; ++r) acc[nt][r] = 0.f;

    const unsigned short* xr0 = xk0 + dl * xkstride;
    const unsigned short* xr1 = XKDUAL ? (xk1 + dl * xkstride) : nullptr;
    const unsigned short* wb = wt + (size_t)(h2 * HOP + o0) * 8;

    auto xsplat = [&](int k) -> half8 {
        unsigned int xp;
        if (XKDUAL) {
            const float xv = hs2f(xr0[k]) + hs2f(xr1[k]);
            xp = cvt2(xv, xv);
        } else {
            xp = (unsigned int)xr0[k] * 0x10001u;
        }
        uint4 s; s.x = xp; s.y = xp; s.z = xp; s.w = xp;
        return __builtin_bit_cast(half8, s);
    };

    uint4 br[NS][NT];
    auto loadB = [&](int ks, uint4* b) {
        const unsigned short* p = wb + (size_t)ks * (2 * HOP * 8);
        #pragma unroll
        for (int nt = 0; nt < NT; ++nt)
            b[nt] = *(const uint4*)(p + nt * 256);
    };
    auto phase = [&](int p, half8 xs, const uint4* b) {
        const half8 av = xs * q8[p];
        #pragma unroll
        for (int nt = 0; nt < NT; ++nt)
            acc[nt] = __builtin_amdgcn_mfma_f32_32x32x16_f16(
                av, __builtin_bit_cast(half8, b[nt]), acc[nt], 0, 0, 0);
    };

    #pragma unroll
    for (int s = 0; s < NS; ++s) loadB(ks0 + s, br[s]);
    half8 xs0 = xsplat(kb0);

    if constexpr (NS == 12) {
        // 12-slot rotation: slot(phase p) = p % 12; 12-phase double-groups.
        // Trailing reloads past KH read harmlessly into the next ws region
        // (allocated, never consumed).
        constexpr int NIT = KH / 12;
        static_assert(KH % 12 == 0 || KH % 12 == 6, "NS=12 tail must be 0 or 6 phases");
        #pragma unroll 1
        for (int it = 0; it < NIT; ++it) {
            const int g  = ks0 + it * 12;
            const int kb = kb0 + it * 4;
            const half8 xs1 = xsplat(kb + 1);
            phase(0, xs0, br[0]);   loadB(g + 12 + 0,  br[0]);
            phase(1, xs0, br[1]);   loadB(g + 12 + 1,  br[1]);
            phase(2, xs0, br[2]);   loadB(g + 12 + 2,  br[2]);
            const half8 xs2 = xsplat(kb + 2);
            phase(0, xs1, br[3]);   loadB(g + 12 + 3,  br[3]);
            phase(1, xs1, br[4]);   loadB(g + 12 + 4,  br[4]);
            phase(2, xs1, br[5]);   loadB(g + 12 + 5,  br[5]);
            const half8 xs3 = xsplat(kb + 3);
            phase(0, xs2, br[6]);   loadB(g + 12 + 6,  br[6]);
            phase(1, xs2, br[7]);   loadB(g + 12 + 7,  br[7]);
            phase(2, xs2, br[8]);   loadB(g + 12 + 8,  br[8]);
            const half8 xsn = xsplat(kb + 4);   // last iter: feeds the 6-phase tail
            phase(0, xs3, br[9]);   loadB(g + 12 + 9,  br[9]);
            phase(1, xs3, br[10]);  loadB(g + 12 + 10, br[10]);
            phase(2, xs3, br[11]);  loadB(g + 12 + 11, br[11]);
            xs0 = xsn;
        }
        if constexpr (KH % 12 == 6) {
            // slots 0..5 were reloaded in the last iteration with exactly
            // phases ks0+KH-6 .. ks0+KH-1.
            const int kb = kb0 + NIT * 4;
            const half8 xs1 = xsplat(kb + 1);
            phase(0, xs0, br[0]);
            phase(1, xs0, br[1]);
            phase(2, xs0, br[2]);
            phase(0, xs1, br[3]);
            phase(1, xs1, br[4]);
            phase(2, xs1, br[5]);
        }
    } else {
        #pragma unroll 1
        for (int it = 0; it < KH / 6; ++it) {
            const int g  = ks0 + it * 6;
            const int kb = kb0 + it * 2;
            const half8 xs1 = xsplat(kb + 1);
            phase(0, xs0, br[0 % NS]);  loadB(g + NS + 0, br[0 % NS]);
            phase(1, xs0, br[1 % NS]);  loadB(g + NS + 1, br[1 % NS]);
            phase(2, xs0, br[2 % NS]);  loadB(g + NS + 2, br[2 % NS]);
            const half8 xsn = xsplat(kb + 2);   // in-row-pad at last iter (dead value)
            phase(0, xs1, br[3 % NS]);  loadB(g + NS + 3, br[3 % NS]);
            phase(1, xs1, br[4 % NS]);  loadB(g + NS + 4, br[4 % NS]);
            phase(2, xs1, br[5 % NS]);  loadB(g + NS + 5, br[5 % NS]);
            xs0 = xsn;
        }
    }

    // epilogue
    const int dbase = tile * 32 + 4 * h2;
    if (DUALOUT) {
        unsigned short* ob = khalf ? ob1 : ob0;
        #pragma unroll
        for (int nt = 0; nt < NT; ++nt) {
            const int o = nt * 32 + o0;
            if (o < HO) {
                float s = 0.f;
                #pragma unroll
                for (int r = 0; r < 16; ++r) s += acc[nt][r];
                #pragma unroll
                for (int r = 0; r < 16; ++r)
                    ob[(dbase + (r & 3) + 8 * (r >> 2)) * outstride + o] = f2hs(acc[nt][r]);
                s += __shfl_xor(s, 32, 64);
                if (lane < 32) atomicAdd(&pool[poff + o], s);
            }
        }
        __syncthreads();              // both partial buffers visible
    } else {
        #pragma unroll
        for (int nt = 0; nt < NT; ++nt) {
            const int o = nt * 32 + o0;
            if (o < HO) {
                float s = 0.f;
                #pragma unroll
                for (int r = 0; r < 16; ++r) s += acc[nt][r];
                if (khalf == 0) {
                    #pragma unroll
                    for (int r = 0; r < 16; ++r)
                        ob0[(dbase + (r & 3) + 8 * (r >> 2)) * outstride + o] = f2hs(acc[nt][r]);
                }
                s += __shfl_xor(s, 32, 64);
                if (lane < 32) atomicAdd(&pool[poff + o], s);
            }
        }
        __syncthreads();
        if (khalf == 1) {
            #pragma unroll
            for (int nt = 0; nt < NT; ++nt) {
                const int o = nt * 32 + o0;
                if (o < HO) {
                    #pragma unroll
                    for (int r = 0; r < 16; ++r) {
                        const int idx = (dbase + (r & 3) + 8 * (r >> 2)) * outstride + o;
                        ob0[idx] = f2hs(hs2f(ob0[idx]) + acc[nt][r]);
                    }
                }
            }
        }
        __syncthreads();
    }
}

__global__ __launch_bounds__(512, 4)
void dcin_kernel(const int*   __restrict__ x,
                 const float* __restrict__ emb,
                 const unsigned short* __restrict__ ws,
                 const float* __restrict__ lin_w, const float* __restrict__ lin_b,
                 const float* __restrict__ fc1_b,
                 const float* __restrict__ bn1_g, const float* __restrict__ bn1_b,
                 const float* __restrict__ fc2_w, const float* __restrict__ fc2_b,
                 const float* __restrict__ bn2_g, const float* __restrict__ bn2_b,
                 const float* __restrict__ fc3_w, const float* __restrict__ fc3_b,
                 const float* __restrict__ bn3_g, const float* __restrict__ bn3_b,
                 const float* __restrict__ out_w, const float* __restrict__ out_b,
                 float* __restrict__ out)
{
    __shared__ __align__(16) unsigned short x0h  [D * X0S + 16]; // 14368 B
    __shared__ __align__(16) unsigned short bufA0[D * BAS];      // 17664 B (khalf0 partial)
    __shared__ __align__(16) unsigned short bufA1[D * BAS];      // 17664 B (khalf1 partial)
    __shared__ __align__(16) unsigned short bufB [D * BBS];      //  8448 B (L2 khalf0 partial)
    __shared__ __align__(16) unsigned short bufB1[D * BBS];      //  8448 B (L2 khalf1 partial)
    __shared__ float pool_s[PO];
    __shared__ int   sx[M];
    __shared__ float h1s[64], h2s[48], h3s[24];
    float* const red2 = (float*)bufA0;                // 768 floats (bytes 0..3072)
    float* const Gs   = (float*)(bufA0 + 2048);       // 1536 floats (bytes 4096..10240)

    const unsigned short* wt1   = ws;
    const unsigned short* wt2   = ws + E1;
    const unsigned short* fc1b  = ws + E1 + E2 + E3;
    const unsigned short* wt3v  = ws + EW;            // [24][1536] f16

    const int b = blockIdx.x;
    const int t = threadIdx.x;

    if (t < M) sx[t] = x[b * M + t];
    if (t < PO) pool_s[t] = 0.f;
    __syncthreads();

    // gather x0h[dl][j] = f16(emb[sx[j]][dl]), all 128 d; j-fast writes
    for (int i = t; i < M * (D / 4); i += 512) {
        const int c = i / 48;              // float4 index 0..31
        const int j = i - c * 48;
        const float4 v = ((const float4*)(emb + (size_t)sx[j] * D))[c];
        x0h[(4 * c + 0) * X0S + j] = f2hs(v.x);
        x0h[(4 * c + 1) * X0S + j] = f2hs(v.y);
        x0h[(4 * c + 2) * X0S + j] = f2hs(v.z);
        x0h[(4 * c + 3) * X0S + j] = f2hs(v.w);
    }
    __syncthreads();

    // ---- CIN layer 1: symmetric-folded K (96 ksteps), dual-output ----
    cin1_sym(x0h, wt1, bufA0, bufA1, pool_s, t);
    // ---- CIN layer 2: xk = bufA0+bufA1 on read; dual output bufB/bufB1
    //      (one barrier, no RMW); NS=12 deep B prefetch ----
    cin_mfma<K2, H2, 1, HOP2, 12, true, true>(
        x0h, bufA0, bufA1, BAS, wt2, bufB, bufB1, BBS, pool_s, H1, t);
    // bufB/bufB1 = C2 partials; bufA0/A1 dead (red2/Gs alias live from here).

    // ---- layer 3 via Gram: pool3[o] = sum_n G[n] W3[n][o],
    //      G[k][j] = sum_d C2[d][k] * x0h[d][j]  (exact pooling identity),
    //      C2 = bufB + bufB1 summed on read.
    //      Waves 0,1: Gram j-tiles. Waves 2..7: fc1 partials (concurrent). ----
    const int w = t >> 6;
    if (w < 2) {
        const int lane = t & 63, m = lane & 31, h2g = lane >> 5;
        f32x16 g;
        #pragma unroll
        for (int r = 0; r < 16; ++r) g[r] = 0.f;
        #pragma unroll 1
        for (int s = 0; s < 8; ++s) {      // K = 128 d, 16 per MFMA
            us8 a8, b8;
            #pragma unroll
            for (int i = 0; i < 8; ++i) {
                const int d = s * 16 + h2g * 8 + i;
                a8[i] = f2hs(hs2f(bufB [d * BBS + m]) +
                             hs2f(bufB1[d * BBS + m]));  // A[k=m][d] = C2[d][m]
                b8[i] = x0h[d * X0S + w * 32 + m];       // B[d][j=w*32+m]
            }
            g = __builtin_amdgcn_mfma_f32_32x32x16_f16(
                __builtin_bit_cast(half8, a8), __builtin_bit_cast(half8, b8), g, 0, 0, 0);
        }
        #pragma unroll
        for (int r = 0; r < 16; ++r) {
            const int k = (r & 3) + 8 * (r >> 2) + 4 * h2g;
            const int j = w * 32 + m;
            if (j < 48) Gs[k * 48 + j] = g[r];
        }
    } else {
        // fc1 partial (bf16 weights, f16 x0): waves 2..7, 12 parts x 4 fields
        const int tl = t - 128;
        const int u2 = (tl & 31) * 2;
        const int part = tl >> 5;          // 0..11
        float a0 = 0.f, a1 = 0.f;
        for (int j = part * 4; j < part * 4 + 4; ++j) {
            const unsigned short* xr = x0h + j;
            #pragma unroll 8
            for (int d = 0; d < D; ++d) {
                const float xv = hs2f(xr[d * X0S]);
                const unsigned int wp = *(const unsigned int*)(
                    fc1b + ((size_t)j * D + d) * 64 + u2);
                a0 = fmaf(xv, __builtin_bit_cast(float, wp << 16), a0);
                a1 = fmaf(xv, __builtin_bit_cast(float, wp & 0xffff0000u), a1);
            }
        }
        red2[tl * 2]     = a0;
        red2[tl * 2 + 1] = a1;
    }
    __syncthreads();

    // ---- pool3 GEMV (384 thr, contiguous wt3v half8 reads) + h1 combine ----
    if (t < 384) {
        const int o = t % 24, seg = t / 24;   // 16 segs x 96 n's
        const unsigned short* wrow = wt3v + (size_t)o * 1536 + seg * 96;
        const float* gseg = Gs + seg * 96;
        float a = 0.f;
        #pragma unroll 2
        for (int n8 = 0; n8 < 12; ++n8) {
            const us8 wv = *(const us8*)(wrow + n8 * 8);
            #pragma unroll
            for (int i = 0; i < 8; ++i)
                a = fmaf(gseg[n8 * 8 + i], hs2f(wv[i]), a);
        }
        atomicAdd(&pool_s[H1 + H2 + o], a);
    } else if (t < 448) {
        const int uo = t - 384;
        float v = fc1_b[uo];
        #pragma unroll
        for (int p = 0; p < 12; ++p)
            v += red2[(p * 32 + (uo >> 1)) * 2 + (uo & 1)];
        v = fmaxf(v, 0.f);
        h1s[uo] = bn1_g[uo] * v * BN_SCALE + bn1_b[uo];
    }
    __syncthreads();

    if (t < 48) {
        float a = fc2_b[t];
        #pragma unroll 4
        for (int u = 0; u < 64; ++u) a = fmaf(h1s[u], fc2_w[u * 48 + t], a);
        a = tanhf(a);
        h2s[t] = bn2_g[t] * a * BN_SCALE + bn2_b[t];
    }
    __syncthreads();

    if (t < 24) {
        float a = fc3_b[t];
        #pragma unroll 4
        for (int u = 0; u < 48; ++u) a = fmaf(h2s[u], fc3_w[u * 24 + t], a);
        a = tanhf(a);
        h3s[t] = bn3_g[t] * a * BN_SCALE + bn3_b[t];
    }
    __syncthreads();

    if (t == 0) {
        float s = lin_b[0];
        for (int j = 0; j < M; ++j) s += (float)sx[j] * lin_w[j];
        const float slin = tanhf(s);
        float z = out_b[0];
        #pragma unroll 4
        for (int i = 0; i < H3; ++i) z = fmaf(h3s[i], out_w[i], z);
        z = fmaf(slin, out_w[H3], z);
        #pragma unroll 4
        for (int i = 0; i < PO; ++i)
            z = fmaf(pool_s[i], out_w[H3 + 1 + i], z);
        out[b] = 1.f / (1.f + expf(-z));
    }
}

extern "C" void kernel_launch(void* const* d_in, const int* in_sizes, int n_in,
                              void* d_out, int out_size, void* d_ws, size_t ws_size,
                              hipStream_t stream) {
    (void)in_sizes; (void)n_in; (void)ws_size; (void)out_size;
    const int*   x     = (const int*)  d_in[0];
    const float* emb   = (const float*)d_in[1];
    const float* w1    = (const float*)d_in[2];
    const float* w2    = (const float*)d_in[3];
    const float* w3    = (const float*)d_in[4];
    const float* lin_w = (const float*)d_in[5];
    const float* lin_b = (const float*)d_in[6];
    const float* fc1_w = (const float*)d_in[7];
    const float* fc1_b = (const float*)d_in[8];
    const float* bn1_g = (const float*)d_in[9];
    const float* bn1_b = (const float*)d_in[10];
    const float* fc2_w = (const float*)d_in[11];
    const float* fc2_b = (const float*)d_in[12];
    const float* bn2_g = (const float*)d_in[13];
    const float* bn2_b = (const float*)d_in[14];
    const float* fc3_w = (const float*)d_in[15];
    const float* fc3_b = (const float*)d_in[16];
    const float* bn3_g = (const float*)d_in[17];
    const float* bn3_b = (const float*)d_in[18];
    const float* out_w = (const float*)d_in[19];
    const float* out_b = (const float*)d_in[20];
    unsigned short* ws = (unsigned short*)d_ws;

    const int prep_threads = P1 + P2 + P3 + P4 + P5;
    prep_kernel<<<(prep_threads + 255) / 256, 256, 0, stream>>>(w1, w2, w3, fc1_w, ws);

    dcin_kernel<<<512, 512, 0, stream>>>(
        x, emb, ws,
        lin_w, lin_b, fc1_b, bn1_g, bn1_b,
        fc2_w, fc2_b, bn2_g, bn2_b,
        fc3_w, fc3_b, bn3_g, bn3_b,
        out_w, out_b, (float*)d_out);
}

// Round 3
// 168.570 us; speedup vs baseline: 1.1188x; 1.0045x over previous
//
#include <hip/hip_runtime.h>
#include <hip/hip_bf16.h>
#include <math.h>

namespace {
constexpr int M  = 48;    // fields
constexpr int D  = 128;   // embedding dim
constexpr int H1 = 68;
constexpr int H2 = 32;
constexpr int H3 = 24;
constexpr int PO = H1 + H2 + H3;  // 124
constexpr int K2 = H1 * M;   // 3264
constexpr int HOP1 = 96;     // H1 padded to 3 N-tiles of 32
constexpr int HOP2 = 32;
constexpr int HOP3 = 32;
// Layer-1 symmetric fold: lower triangle j<=k, rows padded to 16.
// rows 0..15: 1 kstep, 16..31: 2, 32..47: 3  => 96 ksteps (vs 144 unfolded).
constexpr int KS1 = 96;
// ws layout (ushort elements)
constexpr int E1 = KS1 * 2 * HOP1 * 8;    // 147456  folded w1, n8-major
constexpr int E2 = (K2 / 8) * HOP2 * 8;   // 104448
constexpr int E3 = ((H2 * M) / 8) * HOP3 * 8; // 49152 (n8-major w3, kept for Gram-free paths)
constexpr int EF = (M * D) * 64;          // 393216  fc1_w bf16
constexpr int EW = E1 + E2 + E3 + EF;     // 694272
constexpr int ET = 24 * 1536;             // 36864  wt3v[o][n] f16 (GEMV layout)
constexpr int X0S = 56;  // x0h f16 stride (112 B rows -> 16B-aligned half8 loads)
constexpr int BAS = 69;  // bufA f16 stride
constexpr int BBS = 33;  // bufB f16 stride
constexpr float BN_SCALE = 0.9995003746877732f;  // 1/sqrt(1+1e-3)
// prep thread-space
constexpr int P1 = KS1 * 2 * HOP1;        // 18432
constexpr int P2 = ((H1 * M) / 8) * HOP2; // 13056
constexpr int P3 = ((H2 * M) / 8) * HOP3; //  6144
constexpr int P4 = EF / 8;                // 49152
constexpr int P5 = ET / 8;                //  4608

// kstep -> (row k, jblock p) for the folded layer-1 ordering (k-major).
// base(k): k<16 -> k ; 16..31 -> 16+2(k-16) ; 32..47 -> 48+3(k-32).
constexpr int c1_k(int ks) {
    return (ks < 16) ? ks : (ks < 48) ? 16 + ((ks - 16) >> 1) : 32 + (ks - 48) / 3;
}
constexpr int c1_p(int ks) {
    return (ks < 16) ? 0 : (ks < 48) ? ((ks - 16) & 1) : (ks - 48) % 3;
}
}

typedef __attribute__((ext_vector_type(8)))  _Float16 half8;
typedef __attribute__((ext_vector_type(2)))  __fp16   fp16x2;
typedef __attribute__((ext_vector_type(16))) float f32x16;
typedef __attribute__((ext_vector_type(8)))  unsigned short us8;

static __device__ __forceinline__ unsigned short f2bs(float f) {  // bf16 RNE (fc1 path)
    __hip_bfloat16 h = __float2bfloat16(f);
    return __builtin_bit_cast(unsigned short, h);
}
static __device__ __forceinline__ unsigned short f2hs(float f) {  // f16 RNE
    _Float16 h = (_Float16)f;
    return __builtin_bit_cast(unsigned short, h);
}
static __device__ __forceinline__ float hs2f(unsigned short u) {  // f16 -> f32
    return (float)__builtin_bit_cast(_Float16, u);
}
static __device__ __forceinline__ unsigned int cvt2(float a, float b) {
    fp16x2 h = __builtin_amdgcn_cvt_pkrtz(a, b);
    return __builtin_bit_cast(unsigned int, h);
}

// async global->LDS, 16B per lane, dst = uniform base + lane*16 (m104 rule)
typedef const __attribute__((address_space(1))) void* as1vp;
typedef __attribute__((address_space(3))) void* as3vp;
static __device__ __forceinline__ void gload_lds16(const unsigned short* g, unsigned short* l) {
    __builtin_amdgcn_global_load_lds((as1vp)g, (as3vp)l, 16, 0, 0);
}

// ---------------- prep: transpose+convert weights into d_ws ------------------
// Folded n8-major layout for w1 (symmetric pair-sum), n8-major for w2/w3,
// bf16 copy of fc1_w, plus wt3v[o][n] f16 for the pool3 GEMV.
__global__ __launch_bounds__(256)
void prep_kernel(const float* __restrict__ w1, const float* __restrict__ w2,
                 const float* __restrict__ w3, const float* __restrict__ fc1w,
                 unsigned short* __restrict__ ws)
{
    const int tid = blockIdx.x * 256 + threadIdx.x;
    us8 v;
    if (tid < P1) {
        const int k8 = tid / HOP1, o = tid - k8 * HOP1;  // k8 = 0..191
        const int ks = k8 >> 1, hh = k8 & 1;
        const int k = c1_k(ks), p = c1_p(ks);
        #pragma unroll
        for (int i = 0; i < 8; ++i) {
            const int j = p * 16 + hh * 8 + i;
            float wv = 0.f;
            if (o < H1) {
                if (j < k)       wv = w1[(k * M + j) * H1 + o] + w1[(j * M + k) * H1 + o];
                else if (j == k) wv = w1[(k * M + k) * H1 + o];
            }
            v[i] = f2hs(wv);
        }
        *(uint4*)(ws + (size_t)k8 * (HOP1 * 8) + o * 8) = __builtin_bit_cast(uint4, v);
    } else if (tid < P1 + P2) {
        const int x = tid - P1;
        const int k8 = x >> 5, o = x & 31;
        #pragma unroll
        for (int i = 0; i < 8; ++i)
            v[i] = f2hs(w2[(k8 * 8 + i) * H2 + o]);
        *(uint4*)(ws + E1 + (size_t)k8 * (HOP2 * 8) + o * 8) = __builtin_bit_cast(uint4, v);
    } else if (tid < P1 + P2 + P3) {
        const int x = tid - (P1 + P2);
        const int k8 = x >> 5, o = x & 31;
        #pragma unroll
        for (int i = 0; i < 8; ++i)
            v[i] = (o < H3) ? f2hs(w3[(k8 * 8 + i) * H3 + o]) : (unsigned short)0;
        *(uint4*)(ws + E1 + E2 + (size_t)k8 * (HOP3 * 8) + o * 8) = __builtin_bit_cast(uint4, v);
    } else if (tid < P1 + P2 + P3 + P4) {
        const int x = tid - (P1 + P2 + P3);
        const float4 a = ((const float4*)fc1w)[x * 2];
        const float4 b = ((const float4*)fc1w)[x * 2 + 1];
        v[0] = f2bs(a.x); v[1] = f2bs(a.y); v[2] = f2bs(a.z); v[3] = f2bs(a.w);
        v[4] = f2bs(b.x); v[5] = f2bs(b.y); v[6] = f2bs(b.z); v[7] = f2bs(b.w);
        *(uint4*)(ws + E1 + E2 + E3 + (size_t)x * 8) = __builtin_bit_cast(uint4, v);
    } else if (tid < P1 + P2 + P3 + P4 + P5) {
        const int x = tid - (P1 + P2 + P3 + P4);
        const int o = x / 192, n0 = (x - o * 192) * 8;
        #pragma unroll
        for (int i = 0; i < 8; ++i)
            v[i] = f2hs(w3[(n0 + i) * H3 + o]);
        *(uint4*)(ws + EW + (size_t)o * 1536 + n0) = __builtin_bit_cast(uint4, v);
    }
}

// ---------------- layer-1 (symmetric-folded), LDS-staged B -------------------
// B-stream staged through LDS via global_load_lds: zero-VGPR prefetch depth,
// and the 4 tile-waves share one fetch (4x less L2 traffic). Double-buffered
// groups of 2 ksteps x 2 khalves = 12KB/group; issue g+1 at top of group g,
// consume g, one __syncthreads per group (vmcnt drain window = full group).
template<int KHALF>
__device__ __forceinline__ void cin1_main(
    const half8 (&q8)[3], const unsigned short* __restrict__ xr,
    const unsigned short* __restrict__ wt,
    unsigned short (*stage)[2][2][1536],   // [buf][kh][kk][1536]
    int w, int lane, int foff, f32x16 (&acc)[3])
{
    constexpr int PH0 = KHALF * 48;
    // 12 x 1KB calls per group: c -> (kh = c/6, kk = (c%6)/3, seg = c%3).
    // waves 0..3 issue 2 calls, waves 4..7 issue 1.
    auto issue = [&](int k2, int buf) {   // k2 = group's first kstep (per khalf)
        #pragma unroll
        for (int cc = 0; cc < 2; ++cc) {
            const int c = w + cc * 8;
            if (c < 12) {
                const int kh = c / 6, kk = (c - kh * 6) / 3, seg = c % 3;
                gload_lds16(wt + ((size_t)(kh * 48 + k2 + kk) * 1536 + seg * 512 + lane * 8),
                            &stage[buf][kh][kk][seg * 512]);
            }
        }
    };
    issue(0, 0);
    __syncthreads();      // drains group-0 loads (all waves)
    half8 xs{};
    #pragma unroll
    for (int g = 0; g < 24; ++g) {
        if (g < 23) issue(g * 2 + 2, (g + 1) & 1);
        #pragma unroll
        for (int kk = 0; kk < 2; ++kk) {
            const int gph = PH0 + g * 2 + kk;     // compile-time under unroll
            if (c1_p(gph) == 0) {                 // new row: refresh splat
                const unsigned int xp = (unsigned int)xr[c1_k(gph)] * 0x10001u;
                uint4 s; s.x = xp; s.y = xp; s.z = xp; s.w = xp;
                xs = __builtin_bit_cast(half8, s);
            }
            const unsigned short* bp = &stage[g & 1][KHALF][kk][foff];
            const half8 av = xs * q8[c1_p(gph)];
            #pragma unroll
            for (int nt = 0; nt < 3; ++nt) {
                const uint4 bv = *(const uint4*)(bp + nt * 256);
                acc[nt] = __builtin_amdgcn_mfma_f32_32x32x16_f16(
                    av, __builtin_bit_cast(half8, bv), acc[nt], 0, 0, 0);
            }
        }
        if (g < 23) __syncthreads();   // buf[g&1] free for reuse; g+1 data ready
    }
}

// Layer-1 shell: 8 waves = (tile: 4 x 32 d-rows) x (khalf: rows 0..31 / 32..47).
// Dual-output epilogue (disjoint partial buffers, one barrier, no RMW).
__device__ __forceinline__ void cin1_sym(
    const unsigned short* __restrict__ x0h,
    const unsigned short* __restrict__ wt,
    unsigned short (*stage)[2][2][1536],
    unsigned short* __restrict__ ob0, unsigned short* __restrict__ ob1,
    float* __restrict__ pool, int t)
{
    const int lane  = t & 63;
    const int w     = t >> 6;
    const int tile  = w & 3;
    const int khalf = w >> 2;
    const int o0 = lane & 31, h2 = lane >> 5;
    const int dl = tile * 32 + o0;
    const int foff = (h2 * HOP1 + o0) * 8;

    half8 q8[3];
    #pragma unroll
    for (int p = 0; p < 3; ++p)
        q8[p] = *(const half8*)(x0h + dl * X0S + (2 * p + h2) * 8);

    f32x16 acc[3];
    #pragma unroll
    for (int nt = 0; nt < 3; ++nt)
        #pragma unroll
        for (int r = 0; r < 16; ++r) acc[nt][r] = 0.f;

    const unsigned short* xr = x0h + dl * X0S;

    if (khalf == 0) cin1_main<0>(q8, xr, wt, stage, w, lane, foff, acc);
    else            cin1_main<1>(q8, xr, wt, stage, w, lane, foff, acc);

    const int dbase = tile * 32 + 4 * h2;
    unsigned short* ob = khalf ? ob1 : ob0;
    #pragma unroll
    for (int nt = 0; nt < 3; ++nt) {
        const int o = nt * 32 + o0;
        if (o < H1) {
            float s = 0.f;
            #pragma unroll
            for (int r = 0; r < 16; ++r) s += acc[nt][r];
            #pragma unroll
            for (int r = 0; r < 16; ++r)
                ob[(dbase + (r & 3) + 8 * (r >> 2)) * BAS + o] = f2hs(acc[nt][r]);
            s += __shfl_xor(s, 32, 64);
            if (lane < 32) atomicAdd(&pool[o], s);
        }
    }
    __syncthreads();
}

// ---------------- generic CIN layer (used for layer 2) -----------------------
// 8 waves = (tile: 4 x 32 rows over 128 d) x (khalf: 2). A-build: 4 v_pk_mul_f16.
// NS-slot B rotation (NS=12: ~240cy prefetch cover vs ~200cy+ L2 latency).
// DUALOUT: khalf waves store DISJOINT buffers -> single barrier, no RMW.
// XKDUAL: xk = f16(a0)+f16(a1). NO device-scope fences (R10 regression).
template<int KTOT, int HO, int NT, int HOP, int NS, bool DUALOUT, bool XKDUAL>
__device__ __forceinline__ void cin_mfma(
    const unsigned short* __restrict__ x0h,
    const unsigned short* __restrict__ xk0, const unsigned short* __restrict__ xk1,
    int xkstride,
    const unsigned short* __restrict__ wt,
    unsigned short* __restrict__ ob0, unsigned short* __restrict__ ob1,
    int outstride,
    float* __restrict__ pool, int poff, int t)
{
    const int lane  = t & 63;
    const int w     = t >> 6;
    const int tile  = w & 3;
    const int khalf = w >> 2;
    const int o0 = lane & 31, h2 = lane >> 5;
    const int dl = tile * 32 + o0;          // this lane's A-row (local d, 0..127)
    constexpr int KS = KTOT / 16;
    constexpr int KH = KS / 2;
    static_assert(KH % 6 == 0, "K-half must be a multiple of 6 ksteps");
    static_assert(NS == 3 || NS == 6 || NS == 12, "unsupported NS");
    const int ks0 = khalf * KH;
    const int kb0 = ks0 / 3;

    half8 q8[3];
    #pragma unroll
    for (int p = 0; p < 3; ++p)
        q8[p] = *(const half8*)(x0h + dl * X0S + (2 * p + h2) * 8);

    f32x16 acc[NT];
    #pragma unroll
    for (int nt = 0; nt < NT; ++nt)
        #pragma unroll
        for (int r = 0; r < 16; ++r) acc[nt][r] = 0.f;

    const unsigned short* xr0 = xk0 + dl * xkstride;
    const unsigned short* xr1 = XKDUAL ? (xk1 + dl * xkstride) : nullptr;
    const unsigned short* wb = wt + (size_t)(h2 * HOP + o0) * 8;

    auto xsplat = [&](int k) -> half8 {
        unsigned int xp;
        if (XKDUAL) {
            const float xv = hs2f(xr0[k]) + hs2f(xr1[k]);
            xp = cvt2(xv, xv);
        } else {
            xp = (unsigned int)xr0[k] * 0x10001u;
        }
        uint4 s; s.x = xp; s.y = xp; s.z = xp; s.w = xp;
        return __builtin_bit_cast(half8, s);
    };

    uint4 br[NS][NT];
    auto loadB = [&](int ks, uint4* b) {
        const unsigned short* p = wb + (size_t)ks * (2 * HOP * 8);
        #pragma unroll
        for (int nt = 0; nt < NT; ++nt)
            b[nt] = *(const uint4*)(p + nt * 256);
    };
    auto phase = [&](int p, half8 xs, const uint4* b) {
        const half8 av = xs * q8[p];
        #pragma unroll
        for (int nt = 0; nt < NT; ++nt)
            acc[nt] = __builtin_amdgcn_mfma_f32_32x32x16_f16(
                av, __builtin_bit_cast(half8, b[nt]), acc[nt], 0, 0, 0);
    };

    #pragma unroll
    for (int s = 0; s < NS; ++s) loadB(ks0 + s, br[s]);
    half8 xs0 = xsplat(kb0);

    if constexpr (NS == 12) {
        // 12-slot rotation: slot(phase p) = p % 12; 12-phase double-groups.
        // Trailing reloads past KH read harmlessly into the next ws region
        // (allocated, never consumed).
        constexpr int NIT = KH / 12;
        static_assert(KH % 12 == 0 || KH % 12 == 6, "NS=12 tail must be 0 or 6 phases");
        #pragma unroll 1
        for (int it = 0; it < NIT; ++it) {
            const int g  = ks0 + it * 12;
            const int kb = kb0 + it * 4;
            const half8 xs1 = xsplat(kb + 1);
            phase(0, xs0, br[0]);   loadB(g + 12 + 0,  br[0]);
            phase(1, xs0, br[1]);   loadB(g + 12 + 1,  br[1]);
            phase(2, xs0, br[2]);   loadB(g + 12 + 2,  br[2]);
            const half8 xs2 = xsplat(kb + 2);
            phase(0, xs1, br[3]);   loadB(g + 12 + 3,  br[3]);
            phase(1, xs1, br[4]);   loadB(g + 12 + 4,  br[4]);
            phase(2, xs1, br[5]);   loadB(g + 12 + 5,  br[5]);
            const half8 xs3 = xsplat(kb + 3);
            phase(0, xs2, br[6]);   loadB(g + 12 + 6,  br[6]);
            phase(1, xs2, br[7]);   loadB(g + 12 + 7,  br[7]);
            phase(2, xs2, br[8]);   loadB(g + 12 + 8,  br[8]);
            const half8 xsn = xsplat(kb + 4);   // last iter: feeds the 6-phase tail
            phase(0, xs3, br[9]);   loadB(g + 12 + 9,  br[9]);
            phase(1, xs3, br[10]);  loadB(g + 12 + 10, br[10]);
            phase(2, xs3, br[11]);  loadB(g + 12 + 11, br[11]);
            xs0 = xsn;
        }
        if constexpr (KH % 12 == 6) {
            // slots 0..5 were reloaded in the last iteration with exactly
            // phases ks0+KH-6 .. ks0+KH-1.
            const int kb = kb0 + NIT * 4;
            const half8 xs1 = xsplat(kb + 1);
            phase(0, xs0, br[0]);
            phase(1, xs0, br[1]);
            phase(2, xs0, br[2]);
            phase(0, xs1, br[3]);
            phase(1, xs1, br[4]);
            phase(2, xs1, br[5]);
        }
    } else {
        #pragma unroll 1
        for (int it = 0; it < KH / 6; ++it) {
            const int g  = ks0 + it * 6;
            const int kb = kb0 + it * 2;
            const half8 xs1 = xsplat(kb + 1);
            phase(0, xs0, br[0 % NS]);  loadB(g + NS + 0, br[0 % NS]);
            phase(1, xs0, br[1 % NS]);  loadB(g + NS + 1, br[1 % NS]);
            phase(2, xs0, br[2 % NS]);  loadB(g + NS + 2, br[2 % NS]);
            const half8 xsn = xsplat(kb + 2);   // in-row-pad at last iter (dead value)
            phase(0, xs1, br[3 % NS]);  loadB(g + NS + 3, br[3 % NS]);
            phase(1, xs1, br[4 % NS]);  loadB(g + NS + 4, br[4 % NS]);
            phase(2, xs1, br[5 % NS]);  loadB(g + NS + 5, br[5 % NS]);
            xs0 = xsn;
        }
    }

    // epilogue
    const int dbase = tile * 32 + 4 * h2;
    if (DUALOUT) {
        unsigned short* ob = khalf ? ob1 : ob0;
        #pragma unroll
        for (int nt = 0; nt < NT; ++nt) {
            const int o = nt * 32 + o0;
            if (o < HO) {
                float s = 0.f;
                #pragma unroll
                for (int r = 0; r < 16; ++r) s += acc[nt][r];
                #pragma unroll
                for (int r = 0; r < 16; ++r)
                    ob[(dbase + (r & 3) + 8 * (r >> 2)) * outstride + o] = f2hs(acc[nt][r]);
                s += __shfl_xor(s, 32, 64);
                if (lane < 32) atomicAdd(&pool[poff + o], s);
            }
        }
        __syncthreads();              // both partial buffers visible
    } else {
        #pragma unroll
        for (int nt = 0; nt < NT; ++nt) {
            const int o = nt * 32 + o0;
            if (o < HO) {
                float s = 0.f;
                #pragma unroll
                for (int r = 0; r < 16; ++r) s += acc[nt][r];
                if (khalf == 0) {
                    #pragma unroll
                    for (int r = 0; r < 16; ++r)
                        ob0[(dbase + (r & 3) + 8 * (r >> 2)) * outstride + o] = f2hs(acc[nt][r]);
                }
                s += __shfl_xor(s, 32, 64);
                if (lane < 32) atomicAdd(&pool[poff + o], s);
            }
        }
        __syncthreads();
        if (khalf == 1) {
            #pragma unroll
            for (int nt = 0; nt < NT; ++nt) {
                const int o = nt * 32 + o0;
                if (o < HO) {
                    #pragma unroll
                    for (int r = 0; r < 16; ++r) {
                        const int idx = (dbase + (r & 3) + 8 * (r >> 2)) * outstride + o;
                        ob0[idx] = f2hs(hs2f(ob0[idx]) + acc[nt][r]);
                    }
                }
            }
        }
        __syncthreads();
    }
}

__global__ __launch_bounds__(512, 4)
void dcin_kernel(const int*   __restrict__ x,
                 const float* __restrict__ emb,
                 const unsigned short* __restrict__ ws,
                 const float* __restrict__ lin_w, const float* __restrict__ lin_b,
                 const float* __restrict__ fc1_b,
                 const float* __restrict__ bn1_g, const float* __restrict__ bn1_b,
                 const float* __restrict__ fc2_w, const float* __restrict__ fc2_b,
                 const float* __restrict__ bn2_g, const float* __restrict__ bn2_b,
                 const float* __restrict__ fc3_w, const float* __restrict__ fc3_b,
                 const float* __restrict__ bn3_g, const float* __restrict__ bn3_b,
                 const float* __restrict__ out_w, const float* __restrict__ out_b,
                 float* __restrict__ out)
{
    __shared__ __align__(16) unsigned short x0h  [D * X0S + 16]; // 14368 B
    __shared__ __align__(16) unsigned short bufA0[D * BAS];      // 17664 B (khalf0 partial)
    __shared__ __align__(16) unsigned short bufA1[D * BAS];      // 17664 B (khalf1 partial)
    __shared__ __align__(16) unsigned short stage[2][2][2][1536];// 24576 B (L1 B dbuf)
    __shared__ float pool_s[PO];
    __shared__ int   sx[M];
    __shared__ float h1s[64], h2s[48], h3s[24];
    // stage is dead after layer 1 -> layer-2 output partials alias it.
    unsigned short* const bufB  = &stage[0][0][0][0];            // 8448 B
    unsigned short* const bufB1 = bufB + D * BBS;                // 8448 B
    float* const red2 = (float*)bufA0;                // 768 floats (bytes 0..3072)
    float* const Gs   = (float*)(bufA0 + 2048);       // 1536 floats (bytes 4096..10240)

    const unsigned short* wt1   = ws;
    const unsigned short* wt2   = ws + E1;
    const unsigned short* fc1b  = ws + E1 + E2 + E3;
    const unsigned short* wt3v  = ws + EW;            // [24][1536] f16

    const int b = blockIdx.x;
    const int t = threadIdx.x;

    if (t < M) sx[t] = x[b * M + t];
    if (t < PO) pool_s[t] = 0.f;
    __syncthreads();

    // gather x0h[dl][j] = f16(emb[sx[j]][dl]), all 128 d; j-fast writes
    for (int i = t; i < M * (D / 4); i += 512) {
        const int c = i / 48;              // float4 index 0..31
        const int j = i - c * 48;
        const float4 v = ((const float4*)(emb + (size_t)sx[j] * D))[c];
        x0h[(4 * c + 0) * X0S + j] = f2hs(v.x);
        x0h[(4 * c + 1) * X0S + j] = f2hs(v.y);
        x0h[(4 * c + 2) * X0S + j] = f2hs(v.z);
        x0h[(4 * c + 3) * X0S + j] = f2hs(v.w);
    }
    __syncthreads();

    // ---- CIN layer 1: symmetric-folded K (96 ksteps), LDS-staged B ----
    cin1_sym(x0h, wt1, stage, bufA0, bufA1, pool_s, t);
    // ---- CIN layer 2: xk = bufA0+bufA1 on read; dual output bufB/bufB1
    //      (one barrier, no RMW); NS=12 deep B prefetch ----
    cin_mfma<K2, H2, 1, HOP2, 12, true, true>(
        x0h, bufA0, bufA1, BAS, wt2, bufB, bufB1, BBS, pool_s, H1, t);
    // bufB/bufB1 = C2 partials; bufA0/A1 dead (red2/Gs alias live from here).

    // ---- layer 3 via Gram: pool3[o] = sum_n G[n] W3[n][o],
    //      G[k][j] = sum_d C2[d][k] * x0h[d][j]  (exact pooling identity),
    //      C2 = bufB + bufB1 summed on read.
    //      Waves 0,1: Gram j-tiles. Waves 2..7: fc1 partials (concurrent). ----
    const int w = t >> 6;
    if (w < 2) {
        const int lane = t & 63, m = lane & 31, h2g = lane >> 5;
        f32x16 g;
        #pragma unroll
        for (int r = 0; r < 16; ++r) g[r] = 0.f;
        #pragma unroll 1
        for (int s = 0; s < 8; ++s) {      // K = 128 d, 16 per MFMA
            us8 a8, b8;
            #pragma unroll
            for (int i = 0; i < 8; ++i) {
                const int d = s * 16 + h2g * 8 + i;
                a8[i] = f2hs(hs2f(bufB [d * BBS + m]) +
                             hs2f(bufB1[d * BBS + m]));  // A[k=m][d] = C2[d][m]
                b8[i] = x0h[d * X0S + w * 32 + m];       // B[d][j=w*32+m]
            }
            g = __builtin_amdgcn_mfma_f32_32x32x16_f16(
                __builtin_bit_cast(half8, a8), __builtin_bit_cast(half8, b8), g, 0, 0, 0);
        }
        #pragma unroll
        for (int r = 0; r < 16; ++r) {
            const int k = (r & 3) + 8 * (r >> 2) + 4 * h2g;
            const int j = w * 32 + m;
            if (j < 48) Gs[k * 48 + j] = g[r];
        }
    } else {
        // fc1 partial (bf16 weights, f16 x0): waves 2..7, 12 parts x 4 fields
        const int tl = t - 128;
        const int u2 = (tl & 31) * 2;
        const int part = tl >> 5;          // 0..11
        float a0 = 0.f, a1 = 0.f;
        for (int j = part * 4; j < part * 4 + 4; ++j) {
            const unsigned short* xr = x0h + j;
            #pragma unroll 8
            for (int d = 0; d < D; ++d) {
                const float xv = hs2f(xr[d * X0S]);
                const unsigned int wp = *(const unsigned int*)(
                    fc1b + ((size_t)j * D + d) * 64 + u2);
                a0 = fmaf(xv, __builtin_bit_cast(float, wp << 16), a0);
                a1 = fmaf(xv, __builtin_bit_cast(float, wp & 0xffff0000u), a1);
            }
        }
        red2[tl * 2]     = a0;
        red2[tl * 2 + 1] = a1;
    }
    __syncthreads();

    // ---- pool3 GEMV (384 thr, contiguous wt3v half8 reads) + h1 combine ----
    if (t < 384) {
        const int o = t % 24, seg = t / 24;   // 16 segs x 96 n's
        const unsigned short* wrow = wt3v + (size_t)o * 1536 + seg * 96;
        const float* gseg = Gs + seg * 96;
        float a = 0.f;
        #pragma unroll 2
        for (int n8 = 0; n8 < 12; ++n8) {
            const us8 wv = *(const us8*)(wrow + n8 * 8);
            #pragma unroll
            for (int i = 0; i < 8; ++i)
                a = fmaf(gseg[n8 * 8 + i], hs2f(wv[i]), a);
        }
        atomicAdd(&pool_s[H1 + H2 + o], a);
    } else if (t < 448) {
        const int uo = t - 384;
        float v = fc1_b[uo];
        #pragma unroll
        for (int p = 0; p < 12; ++p)
            v += red2[(p * 32 + (uo >> 1)) * 2 + (uo & 1)];
        v = fmaxf(v, 0.f);
        h1s[uo] = bn1_g[uo] * v * BN_SCALE + bn1_b[uo];
    }
    __syncthreads();

    if (t < 48) {
        float a = fc2_b[t];
        #pragma unroll 4
        for (int u = 0; u < 64; ++u) a = fmaf(h1s[u], fc2_w[u * 48 + t], a);
        a = tanhf(a);
        h2s[t] = bn2_g[t] * a * BN_SCALE + bn2_b[t];
    }
    __syncthreads();

    if (t < 24) {
        float a = fc3_b[t];
        #pragma unroll 4
        for (int u = 0; u < 48; ++u) a = fmaf(h2s[u], fc3_w[u * 24 + t], a);
        a = tanhf(a);
        h3s[t] = bn3_g[t] * a * BN_SCALE + bn3_b[t];
    }
    __syncthreads();

    if (t == 0) {
        float s = lin_b[0];
        for (int j = 0; j < M; ++j) s += (float)sx[j] * lin_w[j];
        const float slin = tanhf(s);
        float z = out_b[0];
        #pragma unroll 4
        for (int i = 0; i < H3; ++i) z = fmaf(h3s[i], out_w[i], z);
        z = fmaf(slin, out_w[H3], z);
        #pragma unroll 4
        for (int i = 0; i < PO; ++i)
            z = fmaf(pool_s[i], out_w[H3 + 1 + i], z);
        out[b] = 1.f / (1.f + expf(-z));
    }
}

extern "C" void kernel_launch(void* const* d_in, const int* in_sizes, int n_in,
                              void* d_out, int out_size, void* d_ws, size_t ws_size,
                              hipStream_t stream) {
    (void)in_sizes; (void)n_in; (void)ws_size; (void)out_size;
    const int*   x     = (const int*)  d_in[0];
    const float* emb   = (const float*)d_in[1];
    const float* w1    = (const float*)d_in[2];
    const float* w2    = (const float*)d_in[3];
    const float* w3    = (const float*)d_in[4];
    const float* lin_w = (const float*)d_in[5];
    const float* lin_b = (const float*)d_in[6];
    const float* fc1_w = (const float*)d_in[7];
    const float* fc1_b = (const float*)d_in[8];
    const float* bn1_g = (const float*)d_in[9];
    const float* bn1_b = (const float*)d_in[10];
    const float* fc2_w = (const float*)d_in[11];
    const float* fc2_b = (const float*)d_in[12];
    const float* bn2_g = (const float*)d_in[13];
    const float* bn2_b = (const float*)d_in[14];
    const float* fc3_w = (const float*)d_in[15];
    const float* fc3_b = (const float*)d_in[16];
    const float* bn3_g = (const float*)d_in[17];
    const float* bn3_b = (const float*)d_in[18];
    const float* out_w = (const float*)d_in[19];
    const float* out_b = (const float*)d_in[20];
    unsigned short* ws = (unsigned short*)d_ws;

    const int prep_threads = P1 + P2 + P3 + P4 + P5;
    prep_kernel<<<(prep_threads + 255) / 256, 256, 0, stream>>>(w1, w2, w3, fc1_w, ws);

    dcin_kernel<<<512, 512, 0, stream>>>(
        x, emb, ws,
        lin_w, lin_b, fc1_b, bn1_g, bn1_b,
        fc2_w, fc2_b, bn2_g, bn2_b,
        fc3_w, fc3_b, bn3_g, bn3_b,
        out_w, out_b, (float*)d_out);
}

// Round 4
// 156.903 us; speedup vs baseline: 1.2020x; 1.0744x over previous
//
#include <hip/hip_runtime.h>
#include <hip/hip_bf16.h>
#include <math.h>

namespace {
constexpr int M  = 48;    // fields
constexpr int D  = 128;   // embedding dim
constexpr int H1 = 68;
constexpr int H2 = 32;
constexpr int H3 = 24;
constexpr int PO = H1 + H2 + H3;  // 124
constexpr int K2 = H1 * M;   // 3264
constexpr int HOP1 = 96;     // H1 padded to 3 N-tiles of 32
constexpr int HOP2 = 32;
constexpr int HOP3 = 32;
// Layer-1 symmetric fold: lower triangle j<=k, rows padded to 16.
// rows 0..15: 1 kstep, 16..31: 2, 32..47: 3  => 96 ksteps (vs 144 unfolded).
constexpr int KS1 = 96;
// ws layout (ushort elements)
constexpr int E1 = KS1 * 2 * HOP1 * 8;    // 147456  folded w1, n8-major
constexpr int E2 = (K2 / 8) * HOP2 * 8;   // 104448
constexpr int E3 = ((H2 * M) / 8) * HOP3 * 8; // 49152 (n8-major w3, legacy region)
constexpr int EF = (M * D) * 64;          // 393216  fc1_w f16, [d*6+j8][o][8]
constexpr int EW = E1 + E2 + E3 + EF;     // 694272
constexpr int ET = 24 * 1536;             // 36864  wt3v[o][n] f16 (GEMV layout)
constexpr int X0S = 56;  // x0h f16 stride (112 B rows -> 16B-aligned half8 loads)
constexpr int BAS = 69;  // bufA f16 stride
constexpr int BBS = 33;  // bufB f16 stride
constexpr float BN_SCALE = 0.9995003746877732f;  // 1/sqrt(1+1e-3)
// prep thread-space
constexpr int P1 = KS1 * 2 * HOP1;        // 18432
constexpr int P2 = ((H1 * M) / 8) * HOP2; // 13056
constexpr int P3 = ((H2 * M) / 8) * HOP3; //  6144
constexpr int P4 = EF / 8;                // 49152
constexpr int P5 = ET / 8;                //  4608

// kstep -> (row k, jblock p) for the folded layer-1 ordering (k-major).
constexpr int c1_k(int ks) {
    return (ks < 16) ? ks : (ks < 48) ? 16 + ((ks - 16) >> 1) : 32 + (ks - 48) / 3;
}
constexpr int c1_p(int ks) {
    return (ks < 16) ? 0 : (ks < 48) ? ((ks - 16) & 1) : (ks - 48) % 3;
}
}

typedef __attribute__((ext_vector_type(8)))  _Float16 half8;
typedef __attribute__((ext_vector_type(2)))  __fp16   fp16x2;
typedef __attribute__((ext_vector_type(2)))  _Float16 h2f;
typedef __attribute__((ext_vector_type(16))) float f32x16;
typedef __attribute__((ext_vector_type(8)))  unsigned short us8;

static __device__ __forceinline__ unsigned short f2hs(float f) {  // f16 RNE
    _Float16 h = (_Float16)f;
    return __builtin_bit_cast(unsigned short, h);
}
static __device__ __forceinline__ float hs2f(unsigned short u) {  // f16 -> f32
    return (float)__builtin_bit_cast(_Float16, u);
}
static __device__ __forceinline__ unsigned int cvt2(float a, float b) {
    fp16x2 h = __builtin_amdgcn_cvt_pkrtz(a, b);
    return __builtin_bit_cast(unsigned int, h);
}
static __device__ __forceinline__ float fdot2u(unsigned int x, unsigned int w, float c) {
#if __has_builtin(__builtin_amdgcn_fdot2)
    return __builtin_amdgcn_fdot2(__builtin_bit_cast(h2f, x),
                                  __builtin_bit_cast(h2f, w), c, false);
#else
    const h2f xv = __builtin_bit_cast(h2f, x);
    const h2f wv = __builtin_bit_cast(h2f, w);
    return fmaf((float)xv[0], (float)wv[0], fmaf((float)xv[1], (float)wv[1], c));
#endif
}

// async global->LDS, 16B per lane, dst = uniform base + lane*16 (m104 rule)
typedef const __attribute__((address_space(1))) void* as1vp;
typedef __attribute__((address_space(3))) void* as3vp;
static __device__ __forceinline__ void gload_lds16(const unsigned short* g, unsigned short* l) {
    __builtin_amdgcn_global_load_lds((as1vp)g, (as3vp)l, 16, 0, 0);
}

// ---------------- prep: transpose+convert weights into d_ws ------------------
__global__ __launch_bounds__(256)
void prep_kernel(const float* __restrict__ w1, const float* __restrict__ w2,
                 const float* __restrict__ w3, const float* __restrict__ fc1w,
                 unsigned short* __restrict__ ws)
{
    const int tid = blockIdx.x * 256 + threadIdx.x;
    us8 v;
    if (tid < P1) {
        const int k8 = tid / HOP1, o = tid - k8 * HOP1;  // k8 = 0..191
        const int ks = k8 >> 1, hh = k8 & 1;
        const int k = c1_k(ks), p = c1_p(ks);
        #pragma unroll
        for (int i = 0; i < 8; ++i) {
            const int j = p * 16 + hh * 8 + i;
            float wv = 0.f;
            if (o < H1) {
                if (j < k)       wv = w1[(k * M + j) * H1 + o] + w1[(j * M + k) * H1 + o];
                else if (j == k) wv = w1[(k * M + k) * H1 + o];
            }
            v[i] = f2hs(wv);
        }
        *(uint4*)(ws + (size_t)k8 * (HOP1 * 8) + o * 8) = __builtin_bit_cast(uint4, v);
    } else if (tid < P1 + P2) {
        const int x = tid - P1;
        const int k8 = x >> 5, o = x & 31;
        #pragma unroll
        for (int i = 0; i < 8; ++i)
            v[i] = f2hs(w2[(k8 * 8 + i) * H2 + o]);
        *(uint4*)(ws + E1 + (size_t)k8 * (HOP2 * 8) + o * 8) = __builtin_bit_cast(uint4, v);
    } else if (tid < P1 + P2 + P3) {
        const int x = tid - (P1 + P2);
        const int k8 = x >> 5, o = x & 31;
        #pragma unroll
        for (int i = 0; i < 8; ++i)
            v[i] = (o < H3) ? f2hs(w3[(k8 * 8 + i) * H3 + o]) : (unsigned short)0;
        *(uint4*)(ws + E1 + E2 + (size_t)k8 * (HOP3 * 8) + o * 8) = __builtin_bit_cast(uint4, v);
    } else if (tid < P1 + P2 + P3 + P4) {
        // fc1_w f16, layout [g = d*6+j8][o][8], value i -> fc1w[((j8*8+i)*128+d)*64+o]
        const int x = tid - (P1 + P2 + P3);
        const int g = x >> 6, o = x & 63;
        const int d = g / 6, j8 = g - d * 6;
        #pragma unroll
        for (int i = 0; i < 8; ++i)
            v[i] = f2hs(fc1w[((size_t)(j8 * 8 + i) * D + d) * 64 + o]);
        *(uint4*)(ws + E1 + E2 + E3 + (size_t)x * 8) = __builtin_bit_cast(uint4, v);
    } else if (tid < P1 + P2 + P3 + P4 + P5) {
        const int x = tid - (P1 + P2 + P3 + P4);
        const int o = x / 192, n0 = (x - o * 192) * 8;
        #pragma unroll
        for (int i = 0; i < 8; ++i)
            v[i] = f2hs(w3[(n0 + i) * H3 + o]);
        *(uint4*)(ws + EW + (size_t)o * 1536 + n0) = __builtin_bit_cast(uint4, v);
    }
}

// ---------------- layer-1 (symmetric-folded), LDS-staged B -------------------
template<int KHALF>
__device__ __forceinline__ void cin1_main(
    const half8 (&q8)[3], const unsigned short* __restrict__ xr,
    const unsigned short* __restrict__ wt,
    unsigned short* __restrict__ stg,      // [2 buf][2 kh][2 kk][1536]
    int w, int lane, int foff, f32x16 (&acc)[3])
{
    constexpr int PH0 = KHALF * 48;
    auto issue = [&](int k2, int buf) {   // k2 = group's first kstep (per khalf)
        #pragma unroll
        for (int cc = 0; cc < 2; ++cc) {
            const int c = w + cc * 8;
            if (c < 12) {
                const int kh = c / 6, kk = (c - kh * 6) / 3, seg = c % 3;
                gload_lds16(wt + ((size_t)(kh * 48 + k2 + kk) * 1536 + seg * 512 + lane * 8),
                            stg + buf * 6144 + kh * 3072 + kk * 1536 + seg * 512);
            }
        }
    };
    issue(0, 0);
    __syncthreads();      // drains group-0 loads (all waves)
    half8 xs{};
    #pragma unroll
    for (int g = 0; g < 24; ++g) {
        if (g < 23) issue(g * 2 + 2, (g + 1) & 1);
        #pragma unroll
        for (int kk = 0; kk < 2; ++kk) {
            const int gph = PH0 + g * 2 + kk;     // compile-time under unroll
            if (c1_p(gph) == 0) {                 // new row: refresh splat
                const unsigned int xp = (unsigned int)xr[c1_k(gph)] * 0x10001u;
                uint4 s; s.x = xp; s.y = xp; s.z = xp; s.w = xp;
                xs = __builtin_bit_cast(half8, s);
            }
            const unsigned short* bp = stg + (g & 1) * 6144 + KHALF * 3072 + kk * 1536 + foff;
            const half8 av = xs * q8[c1_p(gph)];
            #pragma unroll
            for (int nt = 0; nt < 3; ++nt) {
                const uint4 bv = *(const uint4*)(bp + nt * 256);
                acc[nt] = __builtin_amdgcn_mfma_f32_32x32x16_f16(
                    av, __builtin_bit_cast(half8, bv), acc[nt], 0, 0, 0);
            }
        }
        if (g < 23) __syncthreads();   // buf[g&1] free for reuse; g+1 data ready
    }
}

__device__ __forceinline__ void cin1_sym(
    const unsigned short* __restrict__ x0h,
    const unsigned short* __restrict__ wt,
    unsigned short* __restrict__ stg,
    unsigned short* __restrict__ ob0, unsigned short* __restrict__ ob1,
    float* __restrict__ pool, int t)
{
    const int lane  = t & 63;
    const int w     = t >> 6;
    const int tile  = w & 3;
    const int khalf = w >> 2;
    const int o0 = lane & 31, h2 = lane >> 5;
    const int dl = tile * 32 + o0;
    const int foff = (h2 * HOP1 + o0) * 8;

    half8 q8[3];
    #pragma unroll
    for (int p = 0; p < 3; ++p)
        q8[p] = *(const half8*)(x0h + dl * X0S + (2 * p + h2) * 8);

    f32x16 acc[3];
    #pragma unroll
    for (int nt = 0; nt < 3; ++nt)
        #pragma unroll
        for (int r = 0; r < 16; ++r) acc[nt][r] = 0.f;

    const unsigned short* xr = x0h + dl * X0S;

    if (khalf == 0) cin1_main<0>(q8, xr, wt, stg, w, lane, foff, acc);
    else            cin1_main<1>(q8, xr, wt, stg, w, lane, foff, acc);

    const int dbase = tile * 32 + 4 * h2;
    unsigned short* ob = khalf ? ob1 : ob0;
    #pragma unroll
    for (int nt = 0; nt < 3; ++nt) {
        const int o = nt * 32 + o0;
        if (o < H1) {
            float s = 0.f;
            #pragma unroll
            for (int r = 0; r < 16; ++r) s += acc[nt][r];
            #pragma unroll
            for (int r = 0; r < 16; ++r)
                ob[(dbase + (r & 3) + 8 * (r >> 2)) * BAS + o] = f2hs(acc[nt][r]);
            s += __shfl_xor(s, 32, 64);
            if (lane < 32) atomicAdd(&pool[o], s);
        }
    }
    __syncthreads();
}

// ---------------- layer-2, LDS-staged B --------------------------------------
// Group = 6 ksteps x 2 khalves = 12 KB, double-buffered in the same stage
// region (24 KB); 17 groups (KH=102). Dedupes the 4x tile-wave redundancy at
// L2 and gives a 6-phase latency window with zero VGPR prefetch cost.
// xk = f16(bufA0)+f16(bufA1) on read; dual output bufB/bufB1 (alias stage ->
// barrier before epilogue writes).
__device__ __forceinline__ void cin2_staged(
    const unsigned short* __restrict__ x0h,
    const unsigned short* __restrict__ xkA, const unsigned short* __restrict__ xkB,
    const unsigned short* __restrict__ wt,
    unsigned short* __restrict__ stg,      // [2 buf][2 kh][6 kk][512]
    unsigned short* __restrict__ ob0, unsigned short* __restrict__ ob1,
    float* __restrict__ pool, int t)
{
    const int lane  = t & 63;
    const int w     = t >> 6;
    const int tile  = w & 3;
    const int khalf = w >> 2;
    const int o0 = lane & 31, h2 = lane >> 5;
    const int dl = tile * 32 + o0;
    constexpr int KH = 102;               // ksteps per khalf (34 xk rows)
    const int foff = (h2 * HOP2 + o0) * 8;

    half8 q8[3];
    #pragma unroll
    for (int p = 0; p < 3; ++p)
        q8[p] = *(const half8*)(x0h + dl * X0S + (2 * p + h2) * 8);

    f32x16 acc;
    #pragma unroll
    for (int r = 0; r < 16; ++r) acc[r] = 0.f;

    const unsigned short* xr0 = xkA + dl * BAS;
    const unsigned short* xr1 = xkB + dl * BAS;

    auto issue = [&](int g) {
        #pragma unroll
        for (int cc = 0; cc < 2; ++cc) {
            const int c = w + cc * 8;
            if (c < 12) {
                const int kh = c / 6, kk = c - kh * 6;
                gload_lds16(wt + ((size_t)(kh * KH + g * 6 + kk)) * 512 + lane * 8,
                            stg + (g & 1) * 6144 + kh * 3072 + kk * 512);
            }
        }
    };
    auto xsplat = [&](int row) -> half8 {
        const float xv = hs2f(xr0[row]) + hs2f(xr1[row]);
        const unsigned int xp = cvt2(xv, xv);
        uint4 s; s.x = xp; s.y = xp; s.z = xp; s.w = xp;
        return __builtin_bit_cast(half8, s);
    };

    issue(0);
    __syncthreads();
    #pragma unroll 1
    for (int g = 0; g < 17; ++g) {
        if (g < 16) issue(g + 1);
        const unsigned short* bp = stg + (g & 1) * 6144 + khalf * 3072 + foff;
        const int row0 = khalf * 34 + g * 2;
        const half8 xs0 = xsplat(row0);
        #pragma unroll
        for (int kk = 0; kk < 3; ++kk) {
            const uint4 bv = *(const uint4*)(bp + kk * 512);
            acc = __builtin_amdgcn_mfma_f32_32x32x16_f16(
                xs0 * q8[kk], __builtin_bit_cast(half8, bv), acc, 0, 0, 0);
        }
        const half8 xs1 = xsplat(row0 + 1);
        #pragma unroll
        for (int kk = 3; kk < 6; ++kk) {
            const uint4 bv = *(const uint4*)(bp + kk * 512);
            acc = __builtin_amdgcn_mfma_f32_32x32x16_f16(
                xs1 * q8[kk - 3], __builtin_bit_cast(half8, bv), acc, 0, 0, 0);
        }
        if (g < 16) __syncthreads();
    }

    // stage reads complete in ALL waves before ob (aliases stage) is written
    __syncthreads();
    const int dbase = tile * 32 + 4 * h2;
    unsigned short* ob = khalf ? ob1 : ob0;
    float s = 0.f;
    #pragma unroll
    for (int r = 0; r < 16; ++r) s += acc[r];
    #pragma unroll
    for (int r = 0; r < 16; ++r)
        ob[(dbase + (r & 3) + 8 * (r >> 2)) * BBS + o0] = f2hs(acc[r]);
    s += __shfl_xor(s, 32, 64);
    if (lane < 32) atomicAdd(&pool[H1 + o0], s);
    __syncthreads();
}

__global__ __launch_bounds__(512, 4)
void dcin_kernel(const int*   __restrict__ x,
                 const float* __restrict__ emb,
                 const unsigned short* __restrict__ ws,
                 const float* __restrict__ lin_w, const float* __restrict__ lin_b,
                 const float* __restrict__ fc1_b,
                 const float* __restrict__ bn1_g, const float* __restrict__ bn1_b,
                 const float* __restrict__ fc2_w, const float* __restrict__ fc2_b,
                 const float* __restrict__ bn2_g, const float* __restrict__ bn2_b,
                 const float* __restrict__ fc3_w, const float* __restrict__ fc3_b,
                 const float* __restrict__ bn3_g, const float* __restrict__ bn3_b,
                 const float* __restrict__ out_w, const float* __restrict__ out_b,
                 float* __restrict__ out)
{
    __shared__ __align__(16) unsigned short x0h  [D * X0S + 16]; // 14368 B
    __shared__ __align__(16) unsigned short bufA0[D * BAS];      // 17664 B (khalf0 partial)
    __shared__ __align__(16) unsigned short bufA1[D * BAS];      // 17664 B (khalf1 partial)
    __shared__ __align__(16) unsigned short stage[2][2][2][1536];// 24576 B (B-stream dbuf)
    __shared__ float pool_s[PO];
    __shared__ int   sx[M];
    __shared__ float h1s[64], h2s[48], h3s[24];
    // stage is dead after each layer's main loop -> layer-2 outputs alias it.
    unsigned short* const stg   = &stage[0][0][0][0];
    unsigned short* const bufB  = stg;                           // 8448 B
    unsigned short* const bufB1 = bufB + D * BBS;                // 8448 B
    float* const red2 = (float*)bufA0;                // 384 floats (bytes 0..1536)
    float* const Gs   = (float*)(bufA0 + 2048);       // 1536 floats (bytes 4096..10240)

    const unsigned short* wt1   = ws;
    const unsigned short* wt2   = ws + E1;
    const unsigned short* fc1b  = ws + E1 + E2 + E3;  // f16 [d*6+j8][o][8]
    const unsigned short* wt3v  = ws + EW;            // [24][1536] f16

    const int b = blockIdx.x;
    const int t = threadIdx.x;

    if (t < M) sx[t] = x[b * M + t];
    if (t < PO) pool_s[t] = 0.f;
    __syncthreads();

    // gather x0h[dl][j] = f16(emb[sx[j]][dl]), all 128 d; j-fast writes
    for (int i = t; i < M * (D / 4); i += 512) {
        const int c = i / 48;              // float4 index 0..31
        const int j = i - c * 48;
        const float4 v = ((const float4*)(emb + (size_t)sx[j] * D))[c];
        x0h[(4 * c + 0) * X0S + j] = f2hs(v.x);
        x0h[(4 * c + 1) * X0S + j] = f2hs(v.y);
        x0h[(4 * c + 2) * X0S + j] = f2hs(v.z);
        x0h[(4 * c + 3) * X0S + j] = f2hs(v.w);
    }
    __syncthreads();

    // ---- CIN layer 1: symmetric-folded K (96 ksteps), LDS-staged B ----
    cin1_sym(x0h, wt1, stg, bufA0, bufA1, pool_s, t);
    // ---- CIN layer 2: LDS-staged B (dedup + 6-phase window) ----
    cin2_staged(x0h, bufA0, bufA1, wt2, stg, bufB, bufB1, pool_s, t);
    // bufB/bufB1 = C2 partials; bufA0/A1 dead (red2/Gs alias live from here).

    // ---- layer 3 via Gram: pool3[o] = sum_n G[n] W3[n][o],
    //      G[k][j] = sum_d C2[d][k] * x0h[d][j]  (exact pooling identity),
    //      C2 = bufB + bufB1 summed on read.
    //      Waves 0,1: Gram j-tiles. Waves 2..7: fc1 partials (concurrent). ----
    const int w = t >> 6;
    if (w < 2) {
        const int lane = t & 63, m = lane & 31, h2g = lane >> 5;
        f32x16 g;
        #pragma unroll
        for (int r = 0; r < 16; ++r) g[r] = 0.f;
        #pragma unroll 1
        for (int s = 0; s < 8; ++s) {      // K = 128 d, 16 per MFMA
            us8 a8, b8;
            #pragma unroll
            for (int i = 0; i < 8; ++i) {
                const int d = s * 16 + h2g * 8 + i;
                a8[i] = f2hs(hs2f(bufB [d * BBS + m]) +
                             hs2f(bufB1[d * BBS + m]));  // A[k=m][d] = C2[d][m]
                b8[i] = x0h[d * X0S + w * 32 + m];       // B[d][j=w*32+m]
            }
            g = __builtin_amdgcn_mfma_f32_32x32x16_f16(
                __builtin_bit_cast(half8, a8), __builtin_bit_cast(half8, b8), g, 0, 0, 0);
        }
        #pragma unroll
        for (int r = 0; r < 16; ++r) {
            const int k = (r & 3) + 8 * (r >> 2) + 4 * h2g;
            const int j = w * 32 + m;
            if (j < 48) Gs[k * 48 + j] = g[r];
        }
    } else {
        // fc1 partial via v_dot2_f32_f16: wave sp owns fields j8 = sp*8..+7,
        // lane = output o; x8 broadcast from x0h row d (uniform addr), w8
        // coalesced 1KB/inst from the [d*6+sp][o][8] layout.
        const int sp = w - 2;              // 0..5
        const int o  = t & 63;
        const unsigned short* xp = x0h + sp * 8;
        const unsigned short* wp = fc1b + (size_t)(sp * 64 + o) * 8;
        float a0 = 0.f, a1 = 0.f;
        #pragma unroll 8
        for (int d = 0; d < D; ++d) {
            const us8 x8 = *(const us8*)(xp + d * X0S);
            const us8 w8 = *(const us8*)(wp + (size_t)d * 3072);
            const uint4 xu = __builtin_bit_cast(uint4, x8);
            const uint4 wu = __builtin_bit_cast(uint4, w8);
            a0 = fdot2u(xu.x, wu.x, a0);
            a1 = fdot2u(xu.y, wu.y, a1);
            a0 = fdot2u(xu.z, wu.z, a0);
            a1 = fdot2u(xu.w, wu.w, a1);
        }
        red2[sp * 64 + o] = a0 + a1;
    }
    __syncthreads();

    // ---- pool3 GEMV (384 thr, contiguous wt3v half8 reads) + h1 combine ----
    if (t < 384) {
        const int o = t % 24, seg = t / 24;   // 16 segs x 96 n's
        const unsigned short* wrow = wt3v + (size_t)o * 1536 + seg * 96;
        const float* gseg = Gs + seg * 96;
        float a = 0.f;
        #pragma unroll 2
        for (int n8 = 0; n8 < 12; ++n8) {
            const us8 wv = *(const us8*)(wrow + n8 * 8);
            #pragma unroll
            for (int i = 0; i < 8; ++i)
                a = fmaf(gseg[n8 * 8 + i], hs2f(wv[i]), a);
        }
        atomicAdd(&pool_s[H1 + H2 + o], a);
    } else if (t < 448) {
        const int uo = t - 384;
        float v = fc1_b[uo];
        #pragma unroll
        for (int p = 0; p < 6; ++p)
            v += red2[p * 64 + uo];
        v = fmaxf(v, 0.f);
        h1s[uo] = bn1_g[uo] * v * BN_SCALE + bn1_b[uo];
    }
    __syncthreads();

    if (t < 48) {
        float a = fc2_b[t];
        #pragma unroll 4
        for (int u = 0; u < 64; ++u) a = fmaf(h1s[u], fc2_w[u * 48 + t], a);
        a = tanhf(a);
        h2s[t] = bn2_g[t] * a * BN_SCALE + bn2_b[t];
    }
    __syncthreads();

    if (t < 24) {
        float a = fc3_b[t];
        #pragma unroll 4
        for (int u = 0; u < 48; ++u) a = fmaf(h2s[u], fc3_w[u * 24 + t], a);
        a = tanhf(a);
        h3s[t] = bn3_g[t] * a * BN_SCALE + bn3_b[t];
    }
    __syncthreads();

    if (t == 0) {
        float s = lin_b[0];
        for (int j = 0; j < M; ++j) s += (float)sx[j] * lin_w[j];
        const float slin = tanhf(s);
        float z = out_b[0];
        #pragma unroll 4
        for (int i = 0; i < H3; ++i) z = fmaf(h3s[i], out_w[i], z);
        z = fmaf(slin, out_w[H3], z);
        #pragma unroll 4
        for (int i = 0; i < PO; ++i)
            z = fmaf(pool_s[i], out_w[H3 + 1 + i], z);
        out[b] = 1.f / (1.f + expf(-z));
    }
}

extern "C" void kernel_launch(void* const* d_in, const int* in_sizes, int n_in,
                              void* d_out, int out_size, void* d_ws, size_t ws_size,
                              hipStream_t stream) {
    (void)in_sizes; (void)n_in; (void)ws_size; (void)out_size;
    const int*   x     = (const int*)  d_in[0];
    const float* emb   = (const float*)d_in[1];
    const float* w1    = (const float*)d_in[2];
    const float* w2    = (const float*)d_in[3];
    const float* w3    = (const float*)d_in[4];
    const float* lin_w = (const float*)d_in[5];
    const float* lin_b = (const float*)d_in[6];
    const float* fc1_w = (const float*)d_in[7];
    const float* fc1_b = (const float*)d_in[8];
    const float* bn1_g = (const float*)d_in[9];
    const float* bn1_b = (const float*)d_in[10];
    const float* fc2_w = (const float*)d_in[11];
    const float* fc2_b = (const float*)d_in[12];
    const float* bn2_g = (const float*)d_in[13];
    const float* bn2_b = (const float*)d_in[14];
    const float* fc3_w = (const float*)d_in[15];
    const float* fc3_b = (const float*)d_in[16];
    const float* bn3_g = (const float*)d_in[17];
    const float* bn3_b = (const float*)d_in[18];
    const float* out_w = (const float*)d_in[19];
    const float* out_b = (const float*)d_in[20];
    unsigned short* ws = (unsigned short*)d_ws;

    const int prep_threads = P1 + P2 + P3 + P4 + P5;
    prep_kernel<<<(prep_threads + 255) / 256, 256, 0, stream>>>(w1, w2, w3, fc1_w, ws);

    dcin_kernel<<<512, 512, 0, stream>>>(
        x, emb, ws,
        lin_w, lin_b, fc1_b, bn1_g, bn1_b,
        fc2_w, fc2_b, bn2_g, bn2_b,
        fc3_w, fc3_b, bn3_g, bn3_b,
        out_w, out_b, (float*)d_out);
}

// Round 5
// 155.993 us; speedup vs baseline: 1.2090x; 1.0058x over previous
//
#include <hip/hip_runtime.h>
#include <hip/hip_bf16.h>
#include <math.h>
#include <utility>

namespace {
constexpr int M  = 48;    // fields
constexpr int D  = 128;   // embedding dim
constexpr int H1 = 68;
constexpr int H2 = 32;
constexpr int H3 = 24;
constexpr int PO = H1 + H2 + H3;  // 124
constexpr int K2 = H1 * M;   // 3264
constexpr int HOP1 = 96;     // H1 padded to 3 N-tiles of 32
constexpr int HOP2 = 32;
constexpr int HOP3 = 32;
// Layer-1 symmetric fold: lower triangle j<=k, rows padded to 16.
// rows 0..15: 1 kstep, 16..31: 2, 32..47: 3  => 96 ksteps (vs 144 unfolded).
constexpr int KS1 = 96;
// ws layout (ushort elements)
constexpr int E1 = KS1 * 2 * HOP1 * 8;    // 147456  folded w1, n8-major
constexpr int E2 = (K2 / 8) * HOP2 * 8;   // 104448
constexpr int E3 = ((H2 * M) / 8) * HOP3 * 8; // 49152 (n8-major w3, legacy region)
constexpr int EF = (M * D) * 64;          // 393216  fc1_w f16, [d*6+j8][o][8]
constexpr int EW = E1 + E2 + E3 + EF;     // 694272
constexpr int ET = 24 * 1536;             // 36864  wt3v[o][n] f16 (GEMV layout)
constexpr int X0S = 56;  // x0h f16 stride (112 B rows -> 16B-aligned half8 loads)
constexpr int BAS = 69;  // bufA f16 stride
constexpr int BBS = 33;  // bufB f16 stride
constexpr float BN_SCALE = 0.9995003746877732f;  // 1/sqrt(1+1e-3)
// prep thread-space
constexpr int P1 = KS1 * 2 * HOP1;        // 18432
constexpr int P2 = ((H1 * M) / 8) * HOP2; // 13056
constexpr int P3 = ((H2 * M) / 8) * HOP3; //  6144
constexpr int P4 = EF / 8;                // 49152
constexpr int P5 = ET / 8;                //  4608

// kstep -> (row k, jblock p) for the folded layer-1 ordering (k-major).
constexpr int c1_k(int ks) {
    return (ks < 16) ? ks : (ks < 48) ? 16 + ((ks - 16) >> 1) : 32 + (ks - 48) / 3;
}
constexpr int c1_p(int ks) {
    return (ks < 16) ? 0 : (ks < 48) ? ((ks - 16) & 1) : (ks - 48) % 3;
}
}

typedef __attribute__((ext_vector_type(8)))  _Float16 half8;
typedef __attribute__((ext_vector_type(2)))  __fp16   fp16x2;
typedef __attribute__((ext_vector_type(2)))  _Float16 h2f;
typedef __attribute__((ext_vector_type(16))) float f32x16;
typedef __attribute__((ext_vector_type(8)))  unsigned short us8;

static __device__ __forceinline__ unsigned short f2hs(float f) {  // f16 RNE
    _Float16 h = (_Float16)f;
    return __builtin_bit_cast(unsigned short, h);
}
static __device__ __forceinline__ float hs2f(unsigned short u) {  // f16 -> f32
    return (float)__builtin_bit_cast(_Float16, u);
}
static __device__ __forceinline__ unsigned int cvt2(float a, float b) {
    fp16x2 h = __builtin_amdgcn_cvt_pkrtz(a, b);
    return __builtin_bit_cast(unsigned int, h);
}
static __device__ __forceinline__ float fdot2u(unsigned int x, unsigned int w, float c) {
#if __has_builtin(__builtin_amdgcn_fdot2)
    return __builtin_amdgcn_fdot2(__builtin_bit_cast(h2f, x),
                                  __builtin_bit_cast(h2f, w), c, false);
#else
    const h2f xv = __builtin_bit_cast(h2f, x);
    const h2f wv = __builtin_bit_cast(h2f, w);
    return fmaf((float)xv[0], (float)wv[0], fmaf((float)xv[1], (float)wv[1], c));
#endif
}

// async global->LDS, 16B per lane, dst = uniform base + lane*16 (m104 rule)
typedef const __attribute__((address_space(1))) void* as1vp;
typedef __attribute__((address_space(3))) void* as3vp;
static __device__ __forceinline__ void gload_lds16(const unsigned short* g, unsigned short* l) {
    __builtin_amdgcn_global_load_lds((as1vp)g, (as3vp)l, 16, 0, 0);
}

// counted vmem wait (AITER pattern: never vmcnt(0) in steady state)
template<int N>
static __device__ __forceinline__ void wait_vmcnt() {
    asm volatile("s_waitcnt vmcnt(%0)" :: "n"(N) : "memory");
}
// raw barrier WITHOUT the __syncthreads vmcnt(0) drain; compiler memory
// fences on both sides so LDS reads can't cross it.
static __device__ __forceinline__ void cbar() {
    asm volatile("" ::: "memory");
    __builtin_amdgcn_s_barrier();
    asm volatile("" ::: "memory");
}

template<int... Gs, class F>
__device__ __forceinline__ void static_for(std::integer_sequence<int, Gs...>, F&& f) {
    (f(std::integral_constant<int, Gs>{}), ...);
}

// ---------------- prep: transpose+convert weights into d_ws ------------------
__global__ __launch_bounds__(256)
void prep_kernel(const float* __restrict__ w1, const float* __restrict__ w2,
                 const float* __restrict__ w3, const float* __restrict__ fc1w,
                 unsigned short* __restrict__ ws)
{
    const int tid = blockIdx.x * 256 + threadIdx.x;
    us8 v;
    if (tid < P1) {
        const int k8 = tid / HOP1, o = tid - k8 * HOP1;  // k8 = 0..191
        const int ks = k8 >> 1, hh = k8 & 1;
        const int k = c1_k(ks), p = c1_p(ks);
        #pragma unroll
        for (int i = 0; i < 8; ++i) {
            const int j = p * 16 + hh * 8 + i;
            float wv = 0.f;
            if (o < H1) {
                if (j < k)       wv = w1[(k * M + j) * H1 + o] + w1[(j * M + k) * H1 + o];
                else if (j == k) wv = w1[(k * M + k) * H1 + o];
            }
            v[i] = f2hs(wv);
        }
        *(uint4*)(ws + (size_t)k8 * (HOP1 * 8) + o * 8) = __builtin_bit_cast(uint4, v);
    } else if (tid < P1 + P2) {
        const int x = tid - P1;
        const int k8 = x >> 5, o = x & 31;
        #pragma unroll
        for (int i = 0; i < 8; ++i)
            v[i] = f2hs(w2[(k8 * 8 + i) * H2 + o]);
        *(uint4*)(ws + E1 + (size_t)k8 * (HOP2 * 8) + o * 8) = __builtin_bit_cast(uint4, v);
    } else if (tid < P1 + P2 + P3) {
        const int x = tid - (P1 + P2);
        const int k8 = x >> 5, o = x & 31;
        #pragma unroll
        for (int i = 0; i < 8; ++i)
            v[i] = (o < H3) ? f2hs(w3[(k8 * 8 + i) * H3 + o]) : (unsigned short)0;
        *(uint4*)(ws + E1 + E2 + (size_t)k8 * (HOP3 * 8) + o * 8) = __builtin_bit_cast(uint4, v);
    } else if (tid < P1 + P2 + P3 + P4) {
        // fc1_w f16, layout [g = d*6+j8][o][8], value i -> fc1w[((j8*8+i)*128+d)*64+o]
        const int x = tid - (P1 + P2 + P3);
        const int g = x >> 6, o = x & 63;
        const int d = g / 6, j8 = g - d * 6;
        #pragma unroll
        for (int i = 0; i < 8; ++i)
            v[i] = f2hs(fc1w[((size_t)(j8 * 8 + i) * D + d) * 64 + o]);
        *(uint4*)(ws + E1 + E2 + E3 + (size_t)x * 8) = __builtin_bit_cast(uint4, v);
    } else if (tid < P1 + P2 + P3 + P4 + P5) {
        const int x = tid - (P1 + P2 + P3 + P4);
        const int o = x / 192, n0 = (x - o * 192) * 8;
        #pragma unroll
        for (int i = 0; i < 8; ++i)
            v[i] = f2hs(w3[(n0 + i) * H3 + o]);
        *(uint4*)(ws + EW + (size_t)o * 1536 + n0) = __builtin_bit_cast(uint4, v);
    }
}

// ---------------- layer-1 (symmetric-folded), counted-vmcnt LDS ring ---------
// 4-slot ring x 6KB (slot = 1 kstep x 2 khalves). Waves 0..5 issue 1 load/slot
// (kh=w/3, seg=w%3). Per iter: vmcnt(2) [2 slots stay in flight] -> raw
// s_barrier (NO drain) -> issue slot g+3 (ring slot consumed pre-barrier last
// iter -> WAR-safe) -> consume slot g. Tail peels vmcnt(1)/vmcnt(0) at
// compile time. Accumulation order identical to the register-rotation version.
template<int KHALF>
__device__ __forceinline__ void cin1_main(
    const half8 (&q8)[3], const unsigned short* __restrict__ xr,
    const unsigned short* __restrict__ wt,
    unsigned short* __restrict__ stg,
    int w, int lane, int foff, f32x16 (&acc)[3])
{
    const bool ld = (w < 6);
    const int kh = w / 3, seg = w - kh * 3;
    auto issue = [&](int g) {
        if (ld)
            gload_lds16(wt + ((size_t)(kh * 48 + g) * 1536 + seg * 512 + lane * 8),
                        stg + (g & 3) * 3072 + kh * 1536 + seg * 512);
    };
    // prologue slots 0..2 issued by caller before the gather __syncthreads
    static_for(std::make_integer_sequence<int, 48>{}, [&](auto gc) {
        constexpr int G = decltype(gc)::value;
        constexpr int W = (48 - G >= 3) ? 2 : (48 - G - 1);
        if (ld) wait_vmcnt<W>();
        cbar();
        if constexpr (G + 3 < 48) issue(G + 3);
        constexpr int gph = KHALF * 48 + G;
        constexpr int K = c1_k(gph), P = c1_p(gph);
        const unsigned int xp = (unsigned int)xr[K] * 0x10001u;
        uint4 sv; sv.x = xp; sv.y = xp; sv.z = xp; sv.w = xp;
        const half8 xs = __builtin_bit_cast(half8, sv);
        const unsigned short* bp = stg + (G & 3) * 3072 + KHALF * 1536 + foff;
        const half8 av = xs * q8[P];
        #pragma unroll
        for (int nt = 0; nt < 3; ++nt) {
            const uint4 bv = *(const uint4*)(bp + nt * 256);
            acc[nt] = __builtin_amdgcn_mfma_f32_32x32x16_f16(
                av, __builtin_bit_cast(half8, bv), acc[nt], 0, 0, 0);
        }
    });
}

__device__ __forceinline__ void cin1_sym(
    const unsigned short* __restrict__ x0h,
    const unsigned short* __restrict__ wt,
    unsigned short* __restrict__ stg,
    unsigned short* __restrict__ ob0, unsigned short* __restrict__ ob1,
    float* __restrict__ pool, int t)
{
    const int lane  = t & 63;
    const int w     = t >> 6;
    const int tile  = w & 3;
    const int khalf = w >> 2;
    const int o0 = lane & 31, h2 = lane >> 5;
    const int dl = tile * 32 + o0;
    const int foff = (h2 * HOP1 + o0) * 8;

    half8 q8[3];
    #pragma unroll
    for (int p = 0; p < 3; ++p)
        q8[p] = *(const half8*)(x0h + dl * X0S + (2 * p + h2) * 8);

    f32x16 acc[3];
    #pragma unroll
    for (int nt = 0; nt < 3; ++nt)
        #pragma unroll
        for (int r = 0; r < 16; ++r) acc[nt][r] = 0.f;

    const unsigned short* xr = x0h + dl * X0S;

    if (khalf == 0) cin1_main<0>(q8, xr, wt, stg, w, lane, foff, acc);
    else            cin1_main<1>(q8, xr, wt, stg, w, lane, foff, acc);

    const int dbase = tile * 32 + 4 * h2;
    unsigned short* ob = khalf ? ob1 : ob0;
    #pragma unroll
    for (int nt = 0; nt < 3; ++nt) {
        const int o = nt * 32 + o0;
        if (o < H1) {
            float s = 0.f;
            #pragma unroll
            for (int r = 0; r < 16; ++r) s += acc[nt][r];
            #pragma unroll
            for (int r = 0; r < 16; ++r)
                ob[(dbase + (r & 3) + 8 * (r >> 2)) * BAS + o] = f2hs(acc[nt][r]);
            s += __shfl_xor(s, 32, 64);
            if (lane < 32) atomicAdd(&pool[o], s);
        }
    }
    __syncthreads();
}

// ---------------- layer-2, counted-vmcnt LDS ring ----------------------------
// 4-slot ring x 6KB (slot = 1 xk-row = 3 ksteps x 2 khalves). Same pipeline
// discipline as layer 1; 34 iterations. Dual output bufB/bufB1 aliases the
// stage -> full-drain __syncthreads before epilogue writes.
__device__ __forceinline__ void cin2_staged(
    const unsigned short* __restrict__ x0h,
    const unsigned short* __restrict__ xkA, const unsigned short* __restrict__ xkB,
    const unsigned short* __restrict__ wt,
    unsigned short* __restrict__ stg,
    unsigned short* __restrict__ ob0, unsigned short* __restrict__ ob1,
    float* __restrict__ pool, int t)
{
    const int lane  = t & 63;
    const int w     = t >> 6;
    const int tile  = w & 3;
    const int khalf = w >> 2;
    const int o0 = lane & 31, h2 = lane >> 5;
    const int dl = tile * 32 + o0;
    const int foff = (h2 * HOP2 + o0) * 8;

    half8 q8[3];
    #pragma unroll
    for (int p = 0; p < 3; ++p)
        q8[p] = *(const half8*)(x0h + dl * X0S + (2 * p + h2) * 8);

    f32x16 acc;
    #pragma unroll
    for (int r = 0; r < 16; ++r) acc[r] = 0.f;

    const unsigned short* xr0 = xkA + dl * BAS;
    const unsigned short* xr1 = xkB + dl * BAS;

    const bool ld = (w < 6);
    const int kh = w / 3, kk = w - kh * 3;
    auto issue = [&](int g) {
        if (ld)
            gload_lds16(wt + ((size_t)(kh * 102 + g * 3 + kk)) * 512 + lane * 8,
                        stg + (g & 3) * 3072 + kh * 1536 + kk * 512);
    };
    auto xsplat = [&](int row) -> half8 {
        const float xv = hs2f(xr0[row]) + hs2f(xr1[row]);
        const unsigned int xp = cvt2(xv, xv);
        uint4 s; s.x = xp; s.y = xp; s.z = xp; s.w = xp;
        return __builtin_bit_cast(half8, s);
    };

    // prologue (entered right after cin1_sym's full-drain __syncthreads,
    // so all stage readers from layer 1 are done -> safe to overwrite)
    issue(0); issue(1); issue(2);
    static_for(std::make_integer_sequence<int, 34>{}, [&](auto gc) {
        constexpr int G = decltype(gc)::value;
        constexpr int W = (34 - G >= 3) ? 2 : (34 - G - 1);
        if (ld) wait_vmcnt<W>();
        cbar();
        if constexpr (G + 3 < 34) issue(G + 3);
        const int row = khalf * 34 + G;
        const half8 xs = xsplat(row);
        const unsigned short* bp = stg + (G & 3) * 3072 + khalf * 1536 + foff;
        #pragma unroll
        for (int p = 0; p < 3; ++p) {
            const uint4 bv = *(const uint4*)(bp + p * 512);
            acc = __builtin_amdgcn_mfma_f32_32x32x16_f16(
                xs * q8[p], __builtin_bit_cast(half8, bv), acc, 0, 0, 0);
        }
    });

    // stage reads complete in ALL waves before ob (aliases stage) is written
    __syncthreads();
    const int dbase = tile * 32 + 4 * h2;
    unsigned short* ob = khalf ? ob1 : ob0;
    float s = 0.f;
    #pragma unroll
    for (int r = 0; r < 16; ++r) s += acc[r];
    #pragma unroll
    for (int r = 0; r < 16; ++r)
        ob[(dbase + (r & 3) + 8 * (r >> 2)) * BBS + o0] = f2hs(acc[r]);
    s += __shfl_xor(s, 32, 64);
    if (lane < 32) atomicAdd(&pool[H1 + o0], s);
    __syncthreads();
}

__global__ __launch_bounds__(512, 4)
void dcin_kernel(const int*   __restrict__ x,
                 const float* __restrict__ emb,
                 const unsigned short* __restrict__ ws,
                 const float* __restrict__ lin_w, const float* __restrict__ lin_b,
                 const float* __restrict__ fc1_b,
                 const float* __restrict__ bn1_g, const float* __restrict__ bn1_b,
                 const float* __restrict__ fc2_w, const float* __restrict__ fc2_b,
                 const float* __restrict__ bn2_g, const float* __restrict__ bn2_b,
                 const float* __restrict__ fc3_w, const float* __restrict__ fc3_b,
                 const float* __restrict__ bn3_g, const float* __restrict__ bn3_b,
                 const float* __restrict__ out_w, const float* __restrict__ out_b,
                 float* __restrict__ out)
{
    __shared__ __align__(16) unsigned short x0h  [D * X0S + 16]; // 14368 B
    __shared__ __align__(16) unsigned short bufA0[D * BAS];      // 17664 B (khalf0 partial)
    __shared__ __align__(16) unsigned short bufA1[D * BAS];      // 17664 B (khalf1 partial)
    __shared__ __align__(16) unsigned short stage[4][2][1536];   // 24576 B (B-ring, 4 slots)
    __shared__ float pool_s[PO];
    __shared__ int   sx[M];
    __shared__ float h1s[64], h2s[48], h3s[24];
    // stage is dead after each layer's main loop -> layer-2 outputs alias it.
    unsigned short* const stg   = &stage[0][0][0];
    unsigned short* const bufB  = stg;                           // 8448 B
    unsigned short* const bufB1 = bufB + D * BBS;                // 8448 B
    float* const red2 = (float*)bufA0;                // 384 floats (bytes 0..1536)
    float* const Gs   = (float*)(bufA0 + 2048);       // 1536 floats (bytes 4096..10240)

    const unsigned short* wt1   = ws;
    const unsigned short* wt2   = ws + E1;
    const unsigned short* fc1b  = ws + E1 + E2 + E3;  // f16 [d*6+j8][o][8]
    const unsigned short* wt3v  = ws + EW;            // [24][1536] f16

    const int b = blockIdx.x;
    const int t = threadIdx.x;

    if (t < M) sx[t] = x[b * M + t];
    if (t < PO) pool_s[t] = 0.f;
    __syncthreads();

    // gather x0h[dl][j] = f16(emb[sx[j]][dl]), all 128 d; j-fast writes
    for (int i = t; i < M * (D / 4); i += 512) {
        const int c = i / 48;              // float4 index 0..31
        const int j = i - c * 48;
        const float4 v = ((const float4*)(emb + (size_t)sx[j] * D))[c];
        x0h[(4 * c + 0) * X0S + j] = f2hs(v.x);
        x0h[(4 * c + 1) * X0S + j] = f2hs(v.y);
        x0h[(4 * c + 2) * X0S + j] = f2hs(v.z);
        x0h[(4 * c + 3) * X0S + j] = f2hs(v.w);
    }
    // L1 prologue: issue ring slots 0..2 (stage cold; drained by the
    // __syncthreads below, which the gather needs anyway)
    {
        const int w = t >> 6, lane = t & 63;
        if (w < 6) {
            const int kh = w / 3, seg = w - kh * 3;
            #pragma unroll
            for (int g = 0; g < 3; ++g)
                gload_lds16(wt1 + ((size_t)(kh * 48 + g) * 1536 + seg * 512 + lane * 8),
                            stg + g * 3072 + kh * 1536 + seg * 512);
        }
    }
    __syncthreads();

    // ---- CIN layer 1: symmetric-folded K (96 ksteps), counted-vmcnt ring ----
    cin1_sym(x0h, wt1, stg, bufA0, bufA1, pool_s, t);
    // ---- CIN layer 2: counted-vmcnt ring (dedup + deep prefetch) ----
    cin2_staged(x0h, bufA0, bufA1, wt2, stg, bufB, bufB1, pool_s, t);
    // bufB/bufB1 = C2 partials; bufA0/A1 dead (red2/Gs alias live from here).

    // ---- layer 3 via Gram: pool3[o] = sum_n G[n] W3[n][o],
    //      G[k][j] = sum_d C2[d][k] * x0h[d][j]  (exact pooling identity),
    //      C2 = bufB + bufB1 summed on read.
    //      Waves 0,1: Gram j-tiles. Waves 2..7: fc1 partials (concurrent). ----
    const int w = t >> 6;
    if (w < 2) {
        const int lane = t & 63, m = lane & 31, h2g = lane >> 5;
        f32x16 g;
        #pragma unroll
        for (int r = 0; r < 16; ++r) g[r] = 0.f;
        #pragma unroll 1
        for (int s = 0; s < 8; ++s) {      // K = 128 d, 16 per MFMA
            us8 a8, b8;
            #pragma unroll
            for (int i = 0; i < 8; ++i) {
                const int d = s * 16 + h2g * 8 + i;
                a8[i] = f2hs(hs2f(bufB [d * BBS + m]) +
                             hs2f(bufB1[d * BBS + m]));  // A[k=m][d] = C2[d][m]
                b8[i] = x0h[d * X0S + w * 32 + m];       // B[d][j=w*32+m]
            }
            g = __builtin_amdgcn_mfma_f32_32x32x16_f16(
                __builtin_bit_cast(half8, a8), __builtin_bit_cast(half8, b8), g, 0, 0, 0);
        }
        #pragma unroll
        for (int r = 0; r < 16; ++r) {
            const int k = (r & 3) + 8 * (r >> 2) + 4 * h2g;
            const int j = w * 32 + m;
            if (j < 48) Gs[k * 48 + j] = g[r];
        }
    } else {
        // fc1 partial via v_dot2_f32_f16: wave sp owns fields j8 = sp*8..+7,
        // lane = output o; x8 broadcast from x0h row d (uniform addr), w8
        // coalesced 1KB/inst from the [d*6+sp][o][8] layout.
        const int sp = w - 2;              // 0..5
        const int o  = t & 63;
        const unsigned short* xp = x0h + sp * 8;
        const unsigned short* wp = fc1b + (size_t)(sp * 64 + o) * 8;
        float a0 = 0.f, a1 = 0.f;
        #pragma unroll 8
        for (int d = 0; d < D; ++d) {
            const us8 x8 = *(const us8*)(xp + d * X0S);
            const us8 w8 = *(const us8*)(wp + (size_t)d * 3072);
            const uint4 xu = __builtin_bit_cast(uint4, x8);
            const uint4 wu = __builtin_bit_cast(uint4, w8);
            a0 = fdot2u(xu.x, wu.x, a0);
            a1 = fdot2u(xu.y, wu.y, a1);
            a0 = fdot2u(xu.z, wu.z, a0);
            a1 = fdot2u(xu.w, wu.w, a1);
        }
        red2[sp * 64 + o] = a0 + a1;
    }
    __syncthreads();

    // ---- pool3 GEMV (384 thr, contiguous wt3v half8 reads) + h1 combine ----
    if (t < 384) {
        const int o = t % 24, seg = t / 24;   // 16 segs x 96 n's
        const unsigned short* wrow = wt3v + (size_t)o * 1536 + seg * 96;
        const float* gseg = Gs + seg * 96;
        float a = 0.f;
        #pragma unroll 2
        for (int n8 = 0; n8 < 12; ++n8) {
            const us8 wv = *(const us8*)(wrow + n8 * 8);
            #pragma unroll
            for (int i = 0; i < 8; ++i)
                a = fmaf(gseg[n8 * 8 + i], hs2f(wv[i]), a);
        }
        atomicAdd(&pool_s[H1 + H2 + o], a);
    } else if (t < 448) {
        const int uo = t - 384;
        float v = fc1_b[uo];
        #pragma unroll
        for (int p = 0; p < 6; ++p)
            v += red2[p * 64 + uo];
        v = fmaxf(v, 0.f);
        h1s[uo] = bn1_g[uo] * v * BN_SCALE + bn1_b[uo];
    }
    __syncthreads();

    if (t < 48) {
        float a = fc2_b[t];
        #pragma unroll 4
        for (int u = 0; u < 64; ++u) a = fmaf(h1s[u], fc2_w[u * 48 + t], a);
        a = tanhf(a);
        h2s[t] = bn2_g[t] * a * BN_SCALE + bn2_b[t];
    }
    __syncthreads();

    if (t < 24) {
        float a = fc3_b[t];
        #pragma unroll 4
        for (int u = 0; u < 48; ++u) a = fmaf(h2s[u], fc3_w[u * 24 + t], a);
        a = tanhf(a);
        h3s[t] = bn3_g[t] * a * BN_SCALE + bn3_b[t];
    }
    __syncthreads();

    if (t == 0) {
        float s = lin_b[0];
        for (int j = 0; j < M; ++j) s += (float)sx[j] * lin_w[j];
        const float slin = tanhf(s);
        float z = out_b[0];
        #pragma unroll 4
        for (int i = 0; i < H3; ++i) z = fmaf(h3s[i], out_w[i], z);
        z = fmaf(slin, out_w[H3], z);
        #pragma unroll 4
        for (int i = 0; i < PO; ++i)
            z = fmaf(pool_s[i], out_w[H3 + 1 + i], z);
        out[b] = 1.f / (1.f + expf(-z));
    }
}

extern "C" void kernel_launch(void* const* d_in, const int* in_sizes, int n_in,
                              void* d_out, int out_size, void* d_ws, size_t ws_size,
                              hipStream_t stream) {
    (void)in_sizes; (void)n_in; (void)ws_size; (void)out_size;
    const int*   x     = (const int*)  d_in[0];
    const float* emb   = (const float*)d_in[1];
    const float* w1    = (const float*)d_in[2];
    const float* w2    = (const float*)d_in[3];
    const float* w3    = (const float*)d_in[4];
    const float* lin_w = (const float*)d_in[5];
    const float* lin_b = (const float*)d_in[6];
    const float* fc1_w = (const float*)d_in[7];
    const float* fc1_b = (const float*)d_in[8];
    const float* bn1_g = (const float*)d_in[9];
    const float* bn1_b = (const float*)d_in[10];
    const float* fc2_w = (const float*)d_in[11];
    const float* fc2_b = (const float*)d_in[12];
    const float* bn2_g = (const float*)d_in[13];
    const float* bn2_b = (const float*)d_in[14];
    const float* fc3_w = (const float*)d_in[15];
    const float* fc3_b = (const float*)d_in[16];
    const float* bn3_g = (const float*)d_in[17];
    const float* bn3_b = (const float*)d_in[18];
    const float* out_w = (const float*)d_in[19];
    const float* out_b = (const float*)d_in[20];
    unsigned short* ws = (unsigned short*)d_ws;

    const int prep_threads = P1 + P2 + P3 + P4 + P5;
    prep_kernel<<<(prep_threads + 255) / 256, 256, 0, stream>>>(w1, w2, w3, fc1_w, ws);

    dcin_kernel<<<512, 512, 0, stream>>>(
        x, emb, ws,
        lin_w, lin_b, fc1_b, bn1_g, bn1_b,
        fc2_w, fc2_b, bn2_g, bn2_b,
        fc3_w, fc3_b, bn3_g, bn3_b,
        out_w, out_b, (float*)d_out);
}

// Round 7
// 154.738 us; speedup vs baseline: 1.2188x; 1.0081x over previous
//
#include <hip/hip_runtime.h>
#include <hip/hip_bf16.h>
#include <math.h>

namespace {
constexpr int M  = 48;    // fields
constexpr int D  = 128;   // embedding dim
constexpr int H1 = 68;
constexpr int H2 = 32;
constexpr int H3 = 24;
constexpr int PO = H1 + H2 + H3;  // 124
constexpr int K2 = H1 * M;   // 3264
constexpr int HOP1 = 96;     // H1 padded to 3 N-tiles of 32
constexpr int HOP2 = 32;
// Layer-1 symmetric fold: lower triangle j<=k, rows padded to 16.
// rows 0..15: 1 kstep, 16..31: 2, 32..47: 3  => 96 ksteps (vs 144 unfolded).
constexpr int KS1 = 96;
// ws layout (ushort elements)
constexpr int E1 = KS1 * 2 * HOP1 * 8;    // 147456  folded w1, n8-major
constexpr int E2 = (K2 / 8) * HOP2 * 8;   // 104448  w2, n8-major
// T table (fc1 collapsed over the 48-row emb vocabulary):
//   T[j][v][o] f32, 48*48*64 = 147456 floats = 589824 B, at ws + E1 + E2.
//   Occupies 294912 ushorts < the 442368-ushort legacy (E3+EF) region.
constexpr int E3 = 49152;                 // legacy region sizes (layout-compat)
constexpr int EF = (M * D) * 64;          // 393216
constexpr int EW = E1 + E2 + E3 + EF;     // 694272
constexpr int ET = 24 * 1536;             // 36864  wt3v[o][n] f16 (GEMV layout)
constexpr int X0S = 56;  // x0h f16 stride (112 B rows -> 16B-aligned half8 loads)
constexpr int BAS = 69;  // bufA f16 stride
constexpr int BBS = 33;  // bufB f16 stride
constexpr float BN_SCALE = 0.9995003746877732f;  // 1/sqrt(1+1e-3)
// prep thread-space
constexpr int P1 = KS1 * 2 * HOP1;        // 18432
constexpr int P2 = ((H1 * M) / 8) * HOP2; // 13056
constexpr int PT = 48 * 48 * 64;          // 147456  T table
constexpr int P5 = ET / 8;                //  4608

// kstep -> (row k, jblock p) for the folded layer-1 ordering (k-major).
constexpr int c1_k(int ks) {
    return (ks < 16) ? ks : (ks < 48) ? 16 + ((ks - 16) >> 1) : 32 + (ks - 48) / 3;
}
constexpr int c1_p(int ks) {
    return (ks < 16) ? 0 : (ks < 48) ? ((ks - 16) & 1) : (ks - 48) % 3;
}
}

typedef __attribute__((ext_vector_type(8)))  _Float16 half8;
typedef __attribute__((ext_vector_type(2)))  __fp16   fp16x2;
typedef __attribute__((ext_vector_type(16))) float f32x16;
typedef __attribute__((ext_vector_type(8)))  unsigned short us8;

static __device__ __forceinline__ unsigned short f2hs(float f) {  // f16 RNE
    _Float16 h = (_Float16)f;
    return __builtin_bit_cast(unsigned short, h);
}
static __device__ __forceinline__ float hs2f(unsigned short u) {  // f16 -> f32
    return (float)__builtin_bit_cast(_Float16, u);
}
static __device__ __forceinline__ unsigned int cvt2(float a, float b) {
    fp16x2 h = __builtin_amdgcn_cvt_pkrtz(a, b);
    return __builtin_bit_cast(unsigned int, h);
}

// async global->LDS, 16B per lane, dst = uniform base + lane*16 (m104 rule)
typedef const __attribute__((address_space(1))) void* as1vp;
typedef __attribute__((address_space(3))) void* as3vp;
static __device__ __forceinline__ void gload_lds16(const unsigned short* g, unsigned short* l) {
    __builtin_amdgcn_global_load_lds((as1vp)g, (as3vp)l, 16, 0, 0);
}

// ---------------- prep: transpose+convert weights into d_ws ------------------
// Folded n8-major layout for w1, n8-major w2, the fc1 T-table (f32), and
// wt3v[o][n] f16 for the pool3 GEMV.
__global__ __launch_bounds__(256)
void prep_kernel(const float* __restrict__ w1, const float* __restrict__ w2,
                 const float* __restrict__ w3, const float* __restrict__ fc1w,
                 const float* __restrict__ emb,
                 unsigned short* __restrict__ ws)
{
    const int tid = blockIdx.x * 256 + threadIdx.x;
    us8 v;
    if (tid < P1) {
        const int k8 = tid / HOP1, o = tid - k8 * HOP1;  // k8 = 0..191
        const int ks = k8 >> 1, hh = k8 & 1;
        const int k = c1_k(ks), p = c1_p(ks);
        #pragma unroll
        for (int i = 0; i < 8; ++i) {
            const int j = p * 16 + hh * 8 + i;
            float wv = 0.f;
            if (o < H1) {
                if (j < k)       wv = w1[(k * M + j) * H1 + o] + w1[(j * M + k) * H1 + o];
                else if (j == k) wv = w1[(k * M + k) * H1 + o];
            }
            v[i] = f2hs(wv);
        }
        *(uint4*)(ws + (size_t)k8 * (HOP1 * 8) + o * 8) = __builtin_bit_cast(uint4, v);
    } else if (tid < P1 + P2) {
        const int x = tid - P1;
        const int k8 = x >> 5, o = x & 31;
        #pragma unroll
        for (int i = 0; i < 8; ++i)
            v[i] = f2hs(w2[(k8 * 8 + i) * H2 + o]);
        *(uint4*)(ws + E1 + (size_t)k8 * (HOP2 * 8) + o * 8) = __builtin_bit_cast(uint4, v);
    } else if (tid < P1 + P2 + PT) {
        // T[j][v][o] = sum_d emb[v][d] * fc1w[(j*D+d)*64 + o]  (f32)
        const int x = tid - (P1 + P2);
        const int o = x & 63, jv = x >> 6;
        const int j = jv / 48, vv = jv - j * 48;
        const float* er = emb + (size_t)vv * D;
        const float* wr = fc1w + (size_t)j * D * 64 + o;
        float a = 0.f;
        #pragma unroll 8
        for (int d = 0; d < D; ++d)
            a = fmaf(er[d], wr[(size_t)d * 64], a);
        ((float*)(ws + E1 + E2))[x] = a;
    } else if (tid < P1 + P2 + PT + P5) {
        const int x = tid - (P1 + P2 + PT);
        const int o = x / 192, n0 = (x - o * 192) * 8;
        #pragma unroll
        for (int i = 0; i < 8; ++i)
            v[i] = f2hs(w3[(n0 + i) * H3 + o]);
        *(uint4*)(ws + EW + (size_t)o * 1536 + n0) = __builtin_bit_cast(uint4, v);
    }
}

// ---------------- layer-1 (symmetric-folded), LDS-staged B -------------------
// (R4-proven structure.) Double-buffered groups of 2 ksteps x 2 khalves =
// 12KB/group; issue g+1 at top of group g, consume g, one __syncthreads per
// group.
template<int KHALF>
__device__ __forceinline__ void cin1_main(
    const half8 (&q8)[3], const unsigned short* __restrict__ xr,
    const unsigned short* __restrict__ wt,
    unsigned short* __restrict__ stg,      // [2 buf][2 kh][2 kk][1536]
    int w, int lane, int foff, f32x16 (&acc)[3])
{
    constexpr int PH0 = KHALF * 48;
    auto issue = [&](int k2, int buf) {   // k2 = group's first kstep (per khalf)
        #pragma unroll
        for (int cc = 0; cc < 2; ++cc) {
            const int c = w + cc * 8;
            if (c < 12) {
                const int kh = c / 6, kk = (c - kh * 6) / 3, seg = c % 3;
                gload_lds16(wt + ((size_t)(kh * 48 + k2 + kk) * 1536 + seg * 512 + lane * 8),
                            stg + buf * 6144 + kh * 3072 + kk * 1536 + seg * 512);
            }
        }
    };
    issue(0, 0);
    __syncthreads();      // drains group-0 loads (all waves)
    half8 xs{};
    #pragma unroll
    for (int g = 0; g < 24; ++g) {
        if (g < 23) issue(g * 2 + 2, (g + 1) & 1);
        #pragma unroll
        for (int kk = 0; kk < 2; ++kk) {
            const int gph = PH0 + g * 2 + kk;     // compile-time under unroll
            if (c1_p(gph) == 0) {                 // new row: refresh splat
                const unsigned int xp = (unsigned int)xr[c1_k(gph)] * 0x10001u;
                uint4 s; s.x = xp; s.y = xp; s.z = xp; s.w = xp;
                xs = __builtin_bit_cast(half8, s);
            }
            const unsigned short* bp = stg + (g & 1) * 6144 + KHALF * 3072 + kk * 1536 + foff;
            const half8 av = xs * q8[c1_p(gph)];
            #pragma unroll
            for (int nt = 0; nt < 3; ++nt) {
                const uint4 bv = *(const uint4*)(bp + nt * 256);
                acc[nt] = __builtin_amdgcn_mfma_f32_32x32x16_f16(
                    av, __builtin_bit_cast(half8, bv), acc[nt], 0, 0, 0);
            }
        }
        if (g < 23) __syncthreads();   // buf[g&1] free for reuse; g+1 data ready
    }
}

__device__ __forceinline__ void cin1_sym(
    const unsigned short* __restrict__ x0h,
    const unsigned short* __restrict__ wt,
    unsigned short* __restrict__ stg,
    unsigned short* __restrict__ ob0, unsigned short* __restrict__ ob1,
    float* __restrict__ pool, int t)
{
    const int lane  = t & 63;
    const int w     = t >> 6;
    const int tile  = w & 3;
    const int khalf = w >> 2;
    const int o0 = lane & 31, h2 = lane >> 5;
    const int dl = tile * 32 + o0;
    const int foff = (h2 * HOP1 + o0) * 8;

    half8 q8[3];
    #pragma unroll
    for (int p = 0; p < 3; ++p)
        q8[p] = *(const half8*)(x0h + dl * X0S + (2 * p + h2) * 8);

    f32x16 acc[3];
    #pragma unroll
    for (int nt = 0; nt < 3; ++nt)
        #pragma unroll
        for (int r = 0; r < 16; ++r) acc[nt][r] = 0.f;

    const unsigned short* xr = x0h + dl * X0S;

    if (khalf == 0) cin1_main<0>(q8, xr, wt, stg, w, lane, foff, acc);
    else            cin1_main<1>(q8, xr, wt, stg, w, lane, foff, acc);

    const int dbase = tile * 32 + 4 * h2;
    unsigned short* ob = khalf ? ob1 : ob0;
    #pragma unroll
    for (int nt = 0; nt < 3; ++nt) {
        const int o = nt * 32 + o0;
        if (o < H1) {
            float s = 0.f;
            #pragma unroll
            for (int r = 0; r < 16; ++r) s += acc[nt][r];
            #pragma unroll
            for (int r = 0; r < 16; ++r)
                ob[(dbase + (r & 3) + 8 * (r >> 2)) * BAS + o] = f2hs(acc[nt][r]);
            s += __shfl_xor(s, 32, 64);
            if (lane < 32) atomicAdd(&pool[o], s);
        }
    }
    __syncthreads();
}

// ---------------- layer-2, LDS-staged B (R4-proven structure) ----------------
__device__ __forceinline__ void cin2_staged(
    const unsigned short* __restrict__ x0h,
    const unsigned short* __restrict__ xkA, const unsigned short* __restrict__ xkB,
    const unsigned short* __restrict__ wt,
    unsigned short* __restrict__ stg,      // [2 buf][2 kh][6 kk][512]
    unsigned short* __restrict__ ob0, unsigned short* __restrict__ ob1,
    float* __restrict__ pool, int t)
{
    const int lane  = t & 63;
    const int w     = t >> 6;
    const int tile  = w & 3;
    const int khalf = w >> 2;
    const int o0 = lane & 31, h2 = lane >> 5;
    const int dl = tile * 32 + o0;
    constexpr int KH = 102;               // ksteps per khalf (34 xk rows)
    const int foff = (h2 * HOP2 + o0) * 8;

    half8 q8[3];
    #pragma unroll
    for (int p = 0; p < 3; ++p)
        q8[p] = *(const half8*)(x0h + dl * X0S + (2 * p + h2) * 8);

    f32x16 acc;
    #pragma unroll
    for (int r = 0; r < 16; ++r) acc[r] = 0.f;

    const unsigned short* xr0 = xkA + dl * BAS;
    const unsigned short* xr1 = xkB + dl * BAS;

    auto issue = [&](int g) {
        #pragma unroll
        for (int cc = 0; cc < 2; ++cc) {
            const int c = w + cc * 8;
            if (c < 12) {
                const int kh = c / 6, kk = c - kh * 6;
                gload_lds16(wt + ((size_t)(kh * KH + g * 6 + kk)) * 512 + lane * 8,
                            stg + (g & 1) * 6144 + kh * 3072 + kk * 512);
            }
        }
    };
    auto xsplat = [&](int row) -> half8 {
        const float xv = hs2f(xr0[row]) + hs2f(xr1[row]);
        const unsigned int xp = cvt2(xv, xv);
        uint4 s; s.x = xp; s.y = xp; s.z = xp; s.w = xp;
        return __builtin_bit_cast(half8, s);
    };

    issue(0);
    __syncthreads();
    #pragma unroll 1
    for (int g = 0; g < 17; ++g) {
        if (g < 16) issue(g + 1);
        const unsigned short* bp = stg + (g & 1) * 6144 + khalf * 3072 + foff;
        const int row0 = khalf * 34 + g * 2;
        const half8 xs0 = xsplat(row0);
        #pragma unroll
        for (int kk = 0; kk < 3; ++kk) {
            const uint4 bv = *(const uint4*)(bp + kk * 512);
            acc = __builtin_amdgcn_mfma_f32_32x32x16_f16(
                xs0 * q8[kk], __builtin_bit_cast(half8, bv), acc, 0, 0, 0);
        }
        const half8 xs1 = xsplat(row0 + 1);
        #pragma unroll
        for (int kk = 3; kk < 6; ++kk) {
            const uint4 bv = *(const uint4*)(bp + kk * 512);
            acc = __builtin_amdgcn_mfma_f32_32x32x16_f16(
                xs1 * q8[kk - 3], __builtin_bit_cast(half8, bv), acc, 0, 0, 0);
        }
        if (g < 16) __syncthreads();
    }

    // stage reads complete in ALL waves before ob (aliases stage) is written
    __syncthreads();
    const int dbase = tile * 32 + 4 * h2;
    unsigned short* ob = khalf ? ob1 : ob0;
    float s = 0.f;
    #pragma unroll
    for (int r = 0; r < 16; ++r) s += acc[r];
    #pragma unroll
    for (int r = 0; r < 16; ++r)
        ob[(dbase + (r & 3) + 8 * (r >> 2)) * BBS + o0] = f2hs(acc[r]);
    s += __shfl_xor(s, 32, 64);
    if (lane < 32) atomicAdd(&pool[H1 + o0], s);
    __syncthreads();
}

__global__ __launch_bounds__(512, 4)
void dcin_kernel(const int*   __restrict__ x,
                 const float* __restrict__ emb,
                 const unsigned short* __restrict__ ws,
                 const float* __restrict__ lin_w, const float* __restrict__ lin_b,
                 const float* __restrict__ fc1_b,
                 const float* __restrict__ bn1_g, const float* __restrict__ bn1_b,
                 const float* __restrict__ fc2_w, const float* __restrict__ fc2_b,
                 const float* __restrict__ bn2_g, const float* __restrict__ bn2_b,
                 const float* __restrict__ fc3_w, const float* __restrict__ fc3_b,
                 const float* __restrict__ bn3_g, const float* __restrict__ bn3_b,
                 const float* __restrict__ out_w, const float* __restrict__ out_b,
                 float* __restrict__ out)
{
    __shared__ __align__(16) unsigned short x0h  [D * X0S + 16]; // 14368 B
    __shared__ __align__(16) unsigned short bufA0[D * BAS];      // 17664 B (khalf0 partial)
    __shared__ __align__(16) unsigned short bufA1[D * BAS];      // 17664 B (khalf1 partial)
    __shared__ __align__(16) unsigned short stage[2][2][2][1536];// 24576 B (B-stream dbuf)
    __shared__ float pool_s[PO];
    __shared__ int   sx[M];
    __shared__ float h1s[64], h2s[48], h3s[24];
    // stage is dead after each layer's main loop -> layer-2 outputs alias it.
    unsigned short* const stg   = &stage[0][0][0][0];
    unsigned short* const bufB  = stg;                           // 8448 B
    unsigned short* const bufB1 = bufB + D * BBS;                // 8448 B
    float* const Gs   = (float*)(bufA0 + 2048);       // 1536 floats (bytes 4096..10240)

    const unsigned short* wt1   = ws;
    const unsigned short* wt2   = ws + E1;
    const float*          Tt    = (const float*)(ws + E1 + E2);  // [48][48][64] f32
    const unsigned short* wt3v  = ws + EW;            // [24][1536] f16

    const int b = blockIdx.x;
    const int t = threadIdx.x;

    if (t < M) sx[t] = x[b * M + t];
    if (t < PO) pool_s[t] = 0.f;
    __syncthreads();

    // gather x0h[dl][j] = f16(emb[sx[j]][dl]), all 128 d; j-fast writes
    for (int i = t; i < M * (D / 4); i += 512) {
        const int c = i / 48;              // float4 index 0..31
        const int j = i - c * 48;
        const float4 v = ((const float4*)(emb + (size_t)sx[j] * D))[c];
        x0h[(4 * c + 0) * X0S + j] = f2hs(v.x);
        x0h[(4 * c + 1) * X0S + j] = f2hs(v.y);
        x0h[(4 * c + 2) * X0S + j] = f2hs(v.z);
        x0h[(4 * c + 3) * X0S + j] = f2hs(v.w);
    }
    __syncthreads();

    // ---- CIN layer 1: symmetric-folded K (96 ksteps), LDS-staged B ----
    cin1_sym(x0h, wt1, stg, bufA0, bufA1, pool_s, t);
    // ---- CIN layer 2: LDS-staged B (dedup + 6-phase window) ----
    cin2_staged(x0h, bufA0, bufA1, wt2, stg, bufB, bufB1, pool_s, t);
    // bufB/bufB1 = C2 partials; bufA0/A1 dead (Gs aliases live from here).

    // ---- layer 3 via Gram: pool3[o] = sum_n G[n] W3[n][o],
    //      G[k][j] = sum_d C2[d][k] * x0h[d][j]  (exact pooling identity),
    //      C2 = bufB + bufB1 summed on read.
    //      Waves 0,1: Gram j-tiles. Wave 2: fc1 via T-table gather. ----
    const int w = t >> 6;
    if (w < 2) {
        const int lane = t & 63, m = lane & 31, h2g = lane >> 5;
        f32x16 g;
        #pragma unroll
        for (int r = 0; r < 16; ++r) g[r] = 0.f;
        #pragma unroll 1
        for (int s = 0; s < 8; ++s) {      // K = 128 d, 16 per MFMA
            us8 a8, b8;
            #pragma unroll
            for (int i = 0; i < 8; ++i) {
                const int d = s * 16 + h2g * 8 + i;
                a8[i] = f2hs(hs2f(bufB [d * BBS + m]) +
                             hs2f(bufB1[d * BBS + m]));  // A[k=m][d] = C2[d][m]
                b8[i] = x0h[d * X0S + w * 32 + m];       // B[d][j=w*32+m]
            }
            g = __builtin_amdgcn_mfma_f32_32x32x16_f16(
                __builtin_bit_cast(half8, a8), __builtin_bit_cast(half8, b8), g, 0, 0, 0);
        }
        #pragma unroll
        for (int r = 0; r < 16; ++r) {
            const int k = (r & 3) + 8 * (r >> 2) + 4 * h2g;
            const int j = w * 32 + m;
            if (j < 48) Gs[k * 48 + j] = g[r];
        }
    } else if (w == 2) {
        // fc1 + relu + bn1, exact f32: fc1[o] = fc1_b[o] + sum_j T[j][sx[j]][o]
        const int o = t & 63;
        float v = fc1_b[o];
        #pragma unroll 8
        for (int j = 0; j < M; ++j)
            v += Tt[(size_t)(j * 48 + sx[j]) * 64 + o];
        v = fmaxf(v, 0.f);
        h1s[o] = bn1_g[o] * v * BN_SCALE + bn1_b[o];
    }
    __syncthreads();

    // ---- pool3 GEMV (384 thr, contiguous wt3v half8 reads) ----
    if (t < 384) {
        const int o = t % 24, seg = t / 24;   // 16 segs x 96 n's
        const unsigned short* wrow = wt3v + (size_t)o * 1536 + seg * 96;
        const float* gseg = Gs + seg * 96;
        float a = 0.f;
        #pragma unroll 2
        for (int n8 = 0; n8 < 12; ++n8) {
            const us8 wv = *(const us8*)(wrow + n8 * 8);
            #pragma unroll
            for (int i = 0; i < 8; ++i)
                a = fmaf(gseg[n8 * 8 + i], hs2f(wv[i]), a);
        }
        atomicAdd(&pool_s[H1 + H2 + o], a);
    }
    __syncthreads();

    if (t < 48) {
        float a = fc2_b[t];
        #pragma unroll 4
        for (int u = 0; u < 64; ++u) a = fmaf(h1s[u], fc2_w[u * 48 + t], a);
        a = tanhf(a);
        h2s[t] = bn2_g[t] * a * BN_SCALE + bn2_b[t];
    }
    __syncthreads();

    if (t < 24) {
        float a = fc3_b[t];
        #pragma unroll 4
        for (int u = 0; u < 48; ++u) a = fmaf(h2s[u], fc3_w[u * 24 + t], a);
        a = tanhf(a);
        h3s[t] = bn3_g[t] * a * BN_SCALE + bn3_b[t];
    }
    __syncthreads();

    if (t == 0) {
        float s = lin_b[0];
        for (int j = 0; j < M; ++j) s += (float)sx[j] * lin_w[j];
        const float slin = tanhf(s);
        float z = out_b[0];
        #pragma unroll 4
        for (int i = 0; i < H3; ++i) z = fmaf(h3s[i], out_w[i], z);
        z = fmaf(slin, out_w[H3], z);
        #pragma unroll 4
        for (int i = 0; i < PO; ++i)
            z = fmaf(pool_s[i], out_w[H3 + 1 + i], z);
        out[b] = 1.f / (1.f + expf(-z));
    }
}

extern "C" void kernel_launch(void* const* d_in, const int* in_sizes, int n_in,
                              void* d_out, int out_size, void* d_ws, size_t ws_size,
                              hipStream_t stream) {
    (void)in_sizes; (void)n_in; (void)ws_size; (void)out_size;
    const int*   x     = (const int*)  d_in[0];
    const float* emb   = (const float*)d_in[1];
    const float* w1    = (const float*)d_in[2];
    const float* w2    = (const float*)d_in[3];
    const float* w3    = (const float*)d_in[4];
    const float* lin_w = (const float*)d_in[5];
    const float* lin_b = (const float*)d_in[6];
    const float* fc1_w = (const float*)d_in[7];
    const float* fc1_b = (const float*)d_in[8];
    const float* bn1_g = (const float*)d_in[9];
    const float* bn1_b = (const float*)d_in[10];
    const float* fc2_w = (const float*)d_in[11];
    const float* fc2_b = (const float*)d_in[12];
    const float* bn2_g = (const float*)d_in[13];
    const float* bn2_b = (const float*)d_in[14];
    const float* fc3_w = (const float*)d_in[15];
    const float* fc3_b = (const float*)d_in[16];
    const float* bn3_g = (const float*)d_in[17];
    const float* bn3_b = (const float*)d_in[18];
    const float* out_w = (const float*)d_in[19];
    const float* out_b = (const float*)d_in[20];
    unsigned short* ws = (unsigned short*)d_ws;

    const int prep_threads = P1 + P2 + PT + P5;
    prep_kernel<<<(prep_threads + 255) / 256, 256, 0, stream>>>(w1, w2, w3, fc1_w, emb, ws);

    dcin_kernel<<<512, 512, 0, stream>>>(
        x, emb, ws,
        lin_w, lin_b, fc1_b, bn1_g, bn1_b,
        fc2_w, fc2_b, bn2_g, bn2_b,
        fc3_w, fc3_b, bn3_g, bn3_b,
        out_w, out_b, (float*)d_out);
}